// Round 12
// baseline (197.549 us; speedup 1.0000x reference)
//
#include <hip/hip_runtime.h>
#include <hip/hip_fp16.h>

#define N_NODES 100000
#define N_EDGES 1250000
#define F_RAW 48
#define F_LOC 16
#define F1 48
#define F_OUT 64

#define NB_BIN 100                           // edge chunks
#define CHUNK (N_EDGES / NB_BIN)             // 12500
#define NBUK 391                             // ceil(N_NODES/256) dst buckets
#define NSCAN (NBUK * NB_BIN)                // 39100
#define NSCAN_PARTS ((NSCAN + 1023) / 1024)  // 39

typedef _Float16 half8_t __attribute__((ext_vector_type(8)));
typedef float floatx4 __attribute__((ext_vector_type(4)));

// ---------------------------------------------------------------------------
// misc: block 0 = edge dtype detect; blocks 1,2 = W1/W2 MFMA-fragment packing
// Wpk[((ct*2+kt)*64 + lane)*8 + j] = W[kt*32 + (lane>>4)*8 + j][ct*16+(lane&15)]
// ---------------------------------------------------------------------------
__device__ void wprep_dev(const float* W, __half* Wpk, int M, int CT) {
    int lane = threadIdx.x;
    if (lane >= 64) return;
    for (int ct = 0; ct < CT; ++ct)
        for (int kt = 0; kt < 2; ++kt)
            for (int j = 0; j < 8; ++j) {
                int k = kt * 32 + (lane >> 4) * 8 + j;
                int c = ct * 16 + (lane & 15);
                Wpk[((ct * 2 + kt) * 64 + lane) * 8 + j] =
                    __float2half(W[k * M + c]);
            }
}

__global__ void k_misc(const unsigned* edges_u32, int* flag,
                       const float* W1, __half* wpk1,
                       const float* W2, __half* wpk2) {
    if (blockIdx.x == 1) {
        wprep_dev(W1, wpk1, F1, 3);
        return;
    }
    if (blockIdx.x == 2) {
        wprep_dev(W2, wpk2, F_OUT, 4);
        return;
    }
    __shared__ int any;
    if (threadIdx.x == 0) any = 0;
    __syncthreads();
    int nz = 0;
    for (int i = threadIdx.x; i < 2048; i += 256) {
        if (edges_u32[2 * i + 1] != 0u) nz = 1;
    }
    if (nz) atomicOr(&any, 1);
    __syncthreads();
    if (threadIdx.x == 0) *flag = any;
}

__device__ __forceinline__ void load_edge(const void* edges, int is32, int e,
                                          int& s, int& d) {
    if (is32) {
        const int* p = (const int*)edges;
        s = p[e];
        d = p[N_EDGES + e];
    } else {
        const long long* p = (const long long*)edges;
        s = (int)p[e];
        d = (int)p[N_EDGES + e];
    }
}

// ---------------------------------------------------------------------------
// pass A: edges -> src32/dst32 (sequential) + per-(bucket,block) histogram.
// ---------------------------------------------------------------------------
__global__ __launch_bounds__(1024) void k_prepA(const void* edges,
                                                const int* flag,
                                                int* __restrict__ src32,
                                                int* __restrict__ dst32,
                                                int* __restrict__ bhist) {
    __shared__ int hist[NBUK];
    int b = blockIdx.x, t = threadIdx.x;
    for (int k = t; k < NBUK; k += 1024) hist[k] = 0;
    __syncthreads();
    int is32 = *flag;
    int e0 = b * CHUNK;
    int e1 = e0 + CHUNK;
    for (int e = e0 + t; e < e1; e += 1024) {
        int s, d;
        load_edge(edges, is32, e, s, d);
        src32[e] = s;
        dst32[e] = d;
        atomicAdd(&hist[d >> 8], 1);
    }
    __syncthreads();
    for (int k = t; k < NBUK; k += 1024) bhist[k * NB_BIN + b] = hist[k];
}

// ---------------------------------------------------------------------------
// generalized exclusive scan over n ints (in-place), 3 kernels.
// ---------------------------------------------------------------------------
__global__ __launch_bounds__(256) void k_gscan_part(const int* __restrict__ in,
                                                    int* __restrict__ part,
                                                    int n) {
    int b = blockIdx.x, t = threadIdx.x;
    int i0 = b * 1024 + t * 4;
    int s = 0;
#pragma unroll
    for (int j = 0; j < 4; ++j) {
        int i = i0 + j;
        if (i < n) s += in[i];
    }
#pragma unroll
    for (int m = 1; m < 64; m <<= 1) s += __shfl_xor(s, m);
    __shared__ int ws[4];
    if ((t & 63) == 0) ws[t >> 6] = s;
    __syncthreads();
    if (t == 0) part[b] = ws[0] + ws[1] + ws[2] + ws[3];
}

__global__ __launch_bounds__(64) void k_gscan_top(int* __restrict__ part,
                                                  int nb) {
    int t = threadIdx.x;
    int v = (t < nb) ? part[t] : 0;
    int x = v;
#pragma unroll
    for (int off = 1; off < 64; off <<= 1) {
        int u = __shfl_up(x, off);
        if (t >= off) x += u;
    }
    if (t < nb) part[t] = x - v;  // exclusive
}

__global__ __launch_bounds__(256) void k_gscan_down(int* __restrict__ data,
                                                    const int* __restrict__ part,
                                                    int n) {
    int b = blockIdx.x, t = threadIdx.x;
    int lane = t & 63, wv = t >> 6;
    int i0 = b * 1024 + t * 4;
    int v[4];
    int s = 0;
#pragma unroll
    for (int j = 0; j < 4; ++j) {
        int i = i0 + j;
        v[j] = (i < n) ? data[i] : 0;
        s += v[j];
    }
    int x = s;
#pragma unroll
    for (int off = 1; off < 64; off <<= 1) {
        int u = __shfl_up(x, off);
        if (lane >= off) x += u;
    }
    __shared__ int ws[4];
    if (lane == 63) ws[wv] = x;
    __syncthreads();
    int woff = 0;
    for (int w = 0; w < wv; ++w) woff += ws[w];
    int run = part[b] + woff + (x - s);
#pragma unroll
    for (int j = 0; j < 4; ++j) {
        int i = i0 + j;
        if (i < n) {
            data[i] = run;
            run += v[j];
        }
    }
}

// ---------------------------------------------------------------------------
// pass C: place edges into bucket-clustered bins. LDS slot counters only.
// ---------------------------------------------------------------------------
__global__ __launch_bounds__(1024) void k_place(const int* __restrict__ src32,
                                                const int* __restrict__ dst32,
                                                const int* __restrict__ bhist,
                                                unsigned* __restrict__ binned) {
    __shared__ int cnt[NBUK];
    int b = blockIdx.x, t = threadIdx.x;
    for (int k = t; k < NBUK; k += 1024) cnt[k] = bhist[k * NB_BIN + b];
    __syncthreads();
    int e0 = b * CHUNK;
    int e1 = e0 + CHUNK;
    for (int e = e0 + t; e < e1; e += 1024) {
        int s = src32[e];
        int d = dst32[e];
        int p = atomicAdd(&cnt[d >> 8], 1);
        binned[p] = ((unsigned)(d & 255) << 17) | (unsigned)s;
    }
}

// ---------------------------------------------------------------------------
// pass D1: one block per bucket (256 nodes): dinv/rowptr + node-ordered csr4.
// ---------------------------------------------------------------------------
__global__ __launch_bounds__(256) void k_bucket(
    const unsigned* __restrict__ binned, const int* __restrict__ bhist,
    float* __restrict__ dinv, int* __restrict__ rowptr,
    unsigned* __restrict__ csr4) {
    int k = blockIdx.x, t = threadIdx.x;
    int lane = t & 63, wv = t >> 6;
    __shared__ int ldeg[256];
    __shared__ int wcnt[256];
    __shared__ int ws4[4];
    int base = bhist[k * NB_BIN];
    int next = (k + 1 < NBUK) ? bhist[(k + 1) * NB_BIN] : N_EDGES;
    int len = next - base;
    ldeg[t] = 0;
    __syncthreads();
    for (int i = t; i < len; i += 256)
        atomicAdd(&ldeg[binned[base + i] >> 17], 1);
    __syncthreads();
    int degv = ldeg[t];
    int x = degv;
#pragma unroll
    for (int off = 1; off < 64; off <<= 1) {
        int u = __shfl_up(x, off);
        if (lane >= off) x += u;
    }
    if (lane == 63) ws4[wv] = x;
    __syncthreads();
    int woff = 0;
    for (int w = 0; w < wv; ++w) woff += ws4[w];
    int excl = woff + x - degv;
    int node = k * 256 + t;
    if (node < N_NODES) {
        dinv[node] = rsqrtf((float)degv + 1.0f);
        rowptr[node] = base + excl;
    }
    wcnt[t] = base + excl;
    __syncthreads();
    for (int i = t; i < len; i += 256) {
        unsigned ent = binned[base + i];
        int dl = ent >> 17;
        int p = atomicAdd(&wcnt[dl], 1);
        csr4[p] = ent & 0x1FFFFu;
    }
    if (k == 0 && t == 0) rowptr[N_NODES] = N_EDGES;
}

// ---------------------------------------------------------------------------
// pass D2: stamp coef in place: csr4[i] = (src<<14) | fp16bits(dinv[src]).
// ---------------------------------------------------------------------------
__global__ __launch_bounds__(256) void k_coef(unsigned* __restrict__ csr4,
                                              const float* __restrict__ dinv) {
    int i = blockIdx.x * 256 + threadIdx.x;
    if (i >= N_EDGES / 4) return;
    uint4 v = reinterpret_cast<uint4*>(csr4)[i];
    v.x = (v.x << 14) | (unsigned)__half_as_ushort(__float2half(dinv[v.x]));
    v.y = (v.y << 14) | (unsigned)__half_as_ushort(__float2half(dinv[v.y]));
    v.z = (v.z << 14) | (unsigned)__half_as_ushort(__float2half(dinv[v.z]));
    v.w = (v.w << 14) | (unsigned)__half_as_ushort(__float2half(dinv[v.w]));
    reinterpret_cast<uint4*>(csr4)[i] = v;
}

// ---------------------------------------------------------------------------
// GEMM1: h1 = concat(feat,loc) @ W1, fp32 inputs read directly.
// writes column-split: h1a = cols 0..31 (64B rows), h1b = cols 32..47 (32B rows)
// ---------------------------------------------------------------------------
__global__ __launch_bounds__(256) void k_gemm1(const float* __restrict__ feat,
                                               const float* __restrict__ loc,
                                               const __half* __restrict__ Wpk,
                                               __half* __restrict__ h1a,
                                               __half* __restrict__ h1b) {
    int wid = threadIdx.x >> 6;
    int lane = threadIdx.x & 63;
    int nb = (blockIdx.x * 4 + wid) * 32;
    if (nb >= N_NODES) return;
    half8_t b[3][2];
#pragma unroll
    for (int ct = 0; ct < 3; ++ct)
#pragma unroll
        for (int kt = 0; kt < 2; ++kt)
            b[ct][kt] = *reinterpret_cast<const half8_t*>(
                Wpk + ((ct * 2 + kt) * 64 + lane) * 8);
    int r = lane & 15;
    int slot = lane >> 4;
    half8_t a[2][2];
#pragma unroll
    for (int rt = 0; rt < 2; ++rt)
#pragma unroll
        for (int kt = 0; kt < 2; ++kt) {
            int sl = kt * 4 + slot;
            int node = nb + rt * 16 + r;
            const float* sp = (sl < 6)
                                  ? feat + (size_t)node * F_RAW + sl * 8
                                  : loc + (size_t)node * F_LOC + (sl - 6) * 8;
            float4 f0 = reinterpret_cast<const float4*>(sp)[0];
            float4 f1 = reinterpret_cast<const float4*>(sp)[1];
            half8_t h;
            h[0] = (_Float16)f0.x;
            h[1] = (_Float16)f0.y;
            h[2] = (_Float16)f0.z;
            h[3] = (_Float16)f0.w;
            h[4] = (_Float16)f1.x;
            h[5] = (_Float16)f1.y;
            h[6] = (_Float16)f1.z;
            h[7] = (_Float16)f1.w;
            a[rt][kt] = h;
        }
    floatx4 acc[2][3];
#pragma unroll
    for (int rt = 0; rt < 2; ++rt)
#pragma unroll
        for (int ct = 0; ct < 3; ++ct) {
            floatx4 z = {0.f, 0.f, 0.f, 0.f};
            z = __builtin_amdgcn_mfma_f32_16x16x32_f16(a[rt][0], b[ct][0], z, 0, 0, 0);
            z = __builtin_amdgcn_mfma_f32_16x16x32_f16(a[rt][1], b[ct][1], z, 0, 0, 0);
            acc[rt][ct] = z;
        }
    int row0 = (lane >> 4) * 4;
    int col = lane & 15;
#pragma unroll
    for (int rt = 0; rt < 2; ++rt)
#pragma unroll
        for (int ct = 0; ct < 3; ++ct)
#pragma unroll
            for (int j = 0; j < 4; ++j) {
                int node = nb + rt * 16 + row0 + j;
                if (ct < 2)
                    h1a[(size_t)node * 32 + ct * 16 + col] =
                        __float2half(acc[rt][ct][j]);
                else
                    h1b[(size_t)node * 16 + col] = __float2half(acc[rt][ct][j]);
            }
}

// ---------------------------------------------------------------------------
// GEMM2: h2 = x1 @ W2 (fp16 in). writes h2a = cols 0..31, h2b = cols 32..63.
// ---------------------------------------------------------------------------
__global__ __launch_bounds__(256) void k_gemm2(const __half* __restrict__ X,
                                               const __half* __restrict__ Wpk,
                                               __half* __restrict__ h2a,
                                               __half* __restrict__ h2b) {
    int wid = threadIdx.x >> 6;
    int lane = threadIdx.x & 63;
    int nb = (blockIdx.x * 4 + wid) * 32;
    if (nb >= N_NODES) return;
    half8_t b[4][2];
#pragma unroll
    for (int ct = 0; ct < 4; ++ct)
#pragma unroll
        for (int kt = 0; kt < 2; ++kt)
            b[ct][kt] = *reinterpret_cast<const half8_t*>(
                Wpk + ((ct * 2 + kt) * 64 + lane) * 8);
    int r = lane & 15;
    int ks = (lane >> 4) * 8;
    half8_t a[2][2];
#pragma unroll
    for (int rt = 0; rt < 2; ++rt)
#pragma unroll
        for (int kt = 0; kt < 2; ++kt)
            a[rt][kt] = *reinterpret_cast<const half8_t*>(
                X + ((size_t)(nb + rt * 16 + r) * 64 + kt * 32 + ks));
    floatx4 acc[2][4];
#pragma unroll
    for (int rt = 0; rt < 2; ++rt)
#pragma unroll
        for (int ct = 0; ct < 4; ++ct) {
            floatx4 z = {0.f, 0.f, 0.f, 0.f};
            z = __builtin_amdgcn_mfma_f32_16x16x32_f16(a[rt][0], b[ct][0], z, 0, 0, 0);
            z = __builtin_amdgcn_mfma_f32_16x16x32_f16(a[rt][1], b[ct][1], z, 0, 0, 0);
            acc[rt][ct] = z;
        }
    int row0 = (lane >> 4) * 4;
    int col = lane & 15;
#pragma unroll
    for (int rt = 0; rt < 2; ++rt)
#pragma unroll
        for (int ct = 0; ct < 4; ++ct)
#pragma unroll
            for (int j = 0; j < 4; ++j) {
                int node = nb + rt * 16 + row0 + j;
                if (ct < 2)
                    h2a[(size_t)node * 32 + ct * 16 + col] =
                        __float2half(acc[rt][ct][j]);
                else
                    h2b[(size_t)node * 32 + (ct - 2) * 16 + col] =
                        __float2half(acc[rt][ct][j]);
            }
}

// ---------------------------------------------------------------------------
// gather helpers
// ---------------------------------------------------------------------------
__device__ __forceinline__ __half2 h2bits(int y) {
    return *reinterpret_cast<__half2*>(&y);
}

__device__ __forceinline__ int as_int_h2(__half2 v) {
    return *reinterpret_cast<int*>(&v);
}

__device__ __forceinline__ __half2 coef2(unsigned A) {
    unsigned b = A & 0x3FFFu;
    return h2bits((int)(b | (b << 16)));
}

__device__ __forceinline__ __half2 shfl_xor_h2(__half2 v, int m) {
    int i = as_int_h2(v);
    i = __shfl_xor(i, m);
    return h2bits(i);
}

// agg1: two-phase gather (h1a 64B rows, h1b 32B rows);
// x1 = [relu(agg*di + self*d2 + b1) (48) | loc (16)] as fp16 rows of 64.
__global__ __launch_bounds__(256) void k_agg1(
    const __half* __restrict__ h1a, const __half* __restrict__ h1b,
    const float* __restrict__ dinv, const int* __restrict__ rowptr,
    const unsigned* __restrict__ csr4, const float* __restrict__ loc,
    const float* __restrict__ b1, __half* __restrict__ x1h) {
    int wave = threadIdx.x >> 6;
    int lane = threadIdx.x & 63;
    int grp = lane >> 3;
    int l8 = lane & 7;
    int node = blockIdx.x * 4 + wave;
    if (node >= N_NODES) return;
    int r0 = rowptr[node], r1 = rowptr[node + 1];
    int len = r1 - r0;
    int L = (len + 7) >> 3;
    int gs = r0 + grp * L;
    int ge = gs + L;
    if (ge > r1) ge = r1;
    float di = dinv[node];
    const char* pa = reinterpret_cast<const char*>(h1a) + l8 * 8;
    const char* pb = reinterpret_cast<const char*>(h1b) + l8 * 4;
    __half2 z2 = __float2half2_rn(0.f);
    // ---- phase A: cols 0..31 ----
    __half2 a0[2] = {z2, z2}, a1[2] = {z2, z2};
    int e = gs;
    for (; e + 1 < ge; e += 2) {
        unsigned A = csr4[e];
        unsigned B = csr4[e + 1];
        int2 vA = *reinterpret_cast<const int2*>(pa + ((A >> 14) << 6));
        int2 vB = *reinterpret_cast<const int2*>(pa + ((B >> 14) << 6));
        __half2 cA = coef2(A), cB = coef2(B);
        a0[0] = __hfma2(h2bits(vA.x), cA, a0[0]);
        a0[1] = __hfma2(h2bits(vA.y), cA, a0[1]);
        a1[0] = __hfma2(h2bits(vB.x), cB, a1[0]);
        a1[1] = __hfma2(h2bits(vB.y), cB, a1[1]);
    }
    if (e < ge) {
        unsigned A = csr4[e];
        int2 vA = *reinterpret_cast<const int2*>(pa + ((A >> 14) << 6));
        __half2 cA = coef2(A);
        a0[0] = __hfma2(h2bits(vA.x), cA, a0[0]);
        a0[1] = __hfma2(h2bits(vA.y), cA, a0[1]);
    }
    a0[0] = __hadd2(a0[0], a1[0]);
    a0[1] = __hadd2(a0[1], a1[1]);
    // ---- phase B: cols 32..47 ----
    __half2 b0 = z2, b1c = z2;
    e = gs;
    for (; e + 1 < ge; e += 2) {
        unsigned A = csr4[e];
        unsigned B = csr4[e + 1];
        int vA = *reinterpret_cast<const int*>(pb + ((A >> 14) << 5));
        int vB = *reinterpret_cast<const int*>(pb + ((B >> 14) << 5));
        b0 = __hfma2(h2bits(vA), coef2(A), b0);
        b1c = __hfma2(h2bits(vB), coef2(B), b1c);
    }
    if (e < ge) {
        unsigned A = csr4[e];
        int vA = *reinterpret_cast<const int*>(pb + ((A >> 14) << 5));
        b0 = __hfma2(h2bits(vA), coef2(A), b0);
    }
    b0 = __hadd2(b0, b1c);
    // ---- reduce across the 8 groups ----
#pragma unroll
    for (int m = 8; m <= 32; m <<= 1) {
        a0[0] = __hadd2(a0[0], shfl_xor_h2(a0[0], m));
        a0[1] = __hadd2(a0[1], shfl_xor_h2(a0[1], m));
        b0 = __hadd2(b0, shfl_xor_h2(b0, m));
    }
    // ---- assemble 8 cols per lane (uniform shfls) ----
    int ai0 = as_int_h2(a0[0]), ai1 = as_int_h2(a0[1]), bi = as_int_h2(b0);
    int m = l8;
    int s0 = (m < 4) ? 2 * m : (m - 4) * 4;
    int t00 = __shfl(ai0, s0), t01 = __shfl(ai1, s0);
    int t10 = __shfl(ai0, s0 + 1), t11 = __shfl(ai1, s0 + 1);
    int u0 = __shfl(bi, s0), u1 = __shfl(bi, s0 + 1);
    int u2 = __shfl(bi, s0 + 2), u3 = __shfl(bi, s0 + 3);
    int w[4];
    if (m < 4) {
        w[0] = t00; w[1] = t01; w[2] = t10; w[3] = t11;
    } else {
        w[0] = u0; w[1] = u1; w[2] = u2; w[3] = u3;
    }
    if (lane < 8) {
        __half2 q[4];
        if (m < 6) {
            float d2 = di * di;
            const float4* b1v = reinterpret_cast<const float4*>(b1);
            float4 bA = b1v[m * 2];
            float4 bB = b1v[m * 2 + 1];
            float bb[8] = {bA.x, bA.y, bA.z, bA.w, bB.x, bB.y, bB.z, bB.w};
            int4 hs = (m < 4)
                          ? *reinterpret_cast<const int4*>(
                                reinterpret_cast<const char*>(h1a) +
                                ((size_t)node << 6) + m * 16)
                          : *reinterpret_cast<const int4*>(
                                reinterpret_cast<const char*>(h1b) +
                                ((size_t)node << 5) + (m - 4) * 16);
            const __half2* hh = reinterpret_cast<const __half2*>(&hs);
#pragma unroll
            for (int j = 0; j < 4; ++j) {
                float2 t = __half22float2(hh[j]);
                float2 ag = __half22float2(h2bits(w[j]));
                float o0 = fmaxf(fmaf(ag.x, di, fmaf(t.x, d2, bb[2 * j])), 0.f);
                float o1 =
                    fmaxf(fmaf(ag.y, di, fmaf(t.y, d2, bb[2 * j + 1])), 0.f);
                q[j] = __halves2half2(__float2half(o0), __float2half(o1));
            }
        } else {
            const float* lp = loc + (size_t)node * F_LOC + (m - 6) * 8;
            float4 f0 = reinterpret_cast<const float4*>(lp)[0];
            float4 f1 = reinterpret_cast<const float4*>(lp)[1];
            q[0] = __halves2half2(__float2half(f0.x), __float2half(f0.y));
            q[1] = __halves2half2(__float2half(f0.z), __float2half(f0.w));
            q[2] = __halves2half2(__float2half(f1.x), __float2half(f1.y));
            q[3] = __halves2half2(__float2half(f1.z), __float2half(f1.w));
        }
        reinterpret_cast<int4*>(x1h)[(size_t)node * 8 + m] =
            *reinterpret_cast<int4*>(q);
    }
}

// agg2: two-phase gather (h2a, h2b both 64B rows) + self + bias -> out (fp32)
__global__ __launch_bounds__(256) void k_out(
    const __half* __restrict__ h2a, const __half* __restrict__ h2b,
    const float* __restrict__ dinv, const int* __restrict__ rowptr,
    const unsigned* __restrict__ csr4, const float* __restrict__ b2,
    float* __restrict__ out) {
    int wave = threadIdx.x >> 6;
    int lane = threadIdx.x & 63;
    int grp = lane >> 3;
    int l8 = lane & 7;
    int node = blockIdx.x * 4 + wave;
    if (node >= N_NODES) return;
    int r0 = rowptr[node], r1 = rowptr[node + 1];
    int len = r1 - r0;
    int L = (len + 7) >> 3;
    int gs = r0 + grp * L;
    int ge = gs + L;
    if (ge > r1) ge = r1;
    float di = dinv[node];
    const char* pa = reinterpret_cast<const char*>(h2a) + l8 * 8;
    const char* pb = reinterpret_cast<const char*>(h2b) + l8 * 8;
    __half2 z2 = __float2half2_rn(0.f);
    // ---- phase A: cols 0..31 ----
    __half2 a0[2] = {z2, z2}, a1[2] = {z2, z2};
    int e = gs;
    for (; e + 1 < ge; e += 2) {
        unsigned A = csr4[e];
        unsigned B = csr4[e + 1];
        int2 vA = *reinterpret_cast<const int2*>(pa + ((A >> 14) << 6));
        int2 vB = *reinterpret_cast<const int2*>(pa + ((B >> 14) << 6));
        __half2 cA = coef2(A), cB = coef2(B);
        a0[0] = __hfma2(h2bits(vA.x), cA, a0[0]);
        a0[1] = __hfma2(h2bits(vA.y), cA, a0[1]);
        a1[0] = __hfma2(h2bits(vB.x), cB, a1[0]);
        a1[1] = __hfma2(h2bits(vB.y), cB, a1[1]);
    }
    if (e < ge) {
        unsigned A = csr4[e];
        int2 vA = *reinterpret_cast<const int2*>(pa + ((A >> 14) << 6));
        __half2 cA = coef2(A);
        a0[0] = __hfma2(h2bits(vA.x), cA, a0[0]);
        a0[1] = __hfma2(h2bits(vA.y), cA, a0[1]);
    }
    a0[0] = __hadd2(a0[0], a1[0]);
    a0[1] = __hadd2(a0[1], a1[1]);
    // ---- phase B: cols 32..63 ----
    __half2 c0[2] = {z2, z2}, c1[2] = {z2, z2};
    e = gs;
    for (; e + 1 < ge; e += 2) {
        unsigned A = csr4[e];
        unsigned B = csr4[e + 1];
        int2 vA = *reinterpret_cast<const int2*>(pb + ((A >> 14) << 6));
        int2 vB = *reinterpret_cast<const int2*>(pb + ((B >> 14) << 6));
        __half2 cA = coef2(A), cB = coef2(B);
        c0[0] = __hfma2(h2bits(vA.x), cA, c0[0]);
        c0[1] = __hfma2(h2bits(vA.y), cA, c0[1]);
        c1[0] = __hfma2(h2bits(vB.x), cB, c1[0]);
        c1[1] = __hfma2(h2bits(vB.y), cB, c1[1]);
    }
    if (e < ge) {
        unsigned A = csr4[e];
        int2 vA = *reinterpret_cast<const int2*>(pb + ((A >> 14) << 6));
        __half2 cA = coef2(A);
        c0[0] = __hfma2(h2bits(vA.x), cA, c0[0]);
        c0[1] = __hfma2(h2bits(vA.y), cA, c0[1]);
    }
    c0[0] = __hadd2(c0[0], c1[0]);
    c0[1] = __hadd2(c0[1], c1[1]);
    // ---- reduce across groups ----
#pragma unroll
    for (int m = 8; m <= 32; m <<= 1) {
        a0[0] = __hadd2(a0[0], shfl_xor_h2(a0[0], m));
        a0[1] = __hadd2(a0[1], shfl_xor_h2(a0[1], m));
        c0[0] = __hadd2(c0[0], shfl_xor_h2(c0[0], m));
        c0[1] = __hadd2(c0[1], shfl_xor_h2(c0[1], m));
    }
    int ai0 = as_int_h2(a0[0]), ai1 = as_int_h2(a0[1]);
    int bi0 = as_int_h2(c0[0]), bi1 = as_int_h2(c0[1]);
    int m = l8;
    int s0 = 2 * (m & 3);
    int tA0 = __shfl(ai0, s0), tA1 = __shfl(ai1, s0);
    int tA2 = __shfl(ai0, s0 + 1), tA3 = __shfl(ai1, s0 + 1);
    int tB0 = __shfl(bi0, s0), tB1 = __shfl(bi1, s0);
    int tB2 = __shfl(bi0, s0 + 1), tB3 = __shfl(bi1, s0 + 1);
    int w[4];
    if (m < 4) {
        w[0] = tA0; w[1] = tA1; w[2] = tA2; w[3] = tA3;
    } else {
        w[0] = tB0; w[1] = tB1; w[2] = tB2; w[3] = tB3;
    }
    if (lane < 8) {
        float d2 = di * di;
        const float4* b2v = reinterpret_cast<const float4*>(b2);
        float4 bA = b2v[m * 2];
        float4 bB = b2v[m * 2 + 1];
        float bb[8] = {bA.x, bA.y, bA.z, bA.w, bB.x, bB.y, bB.z, bB.w};
        int4 hs = (m < 4) ? *reinterpret_cast<const int4*>(
                                reinterpret_cast<const char*>(h2a) +
                                ((size_t)node << 6) + m * 16)
                          : *reinterpret_cast<const int4*>(
                                reinterpret_cast<const char*>(h2b) +
                                ((size_t)node << 6) + (m - 4) * 16);
        const __half2* hh = reinterpret_cast<const __half2*>(&hs);
        float o[8];
#pragma unroll
        for (int j = 0; j < 4; ++j) {
            float2 t = __half22float2(hh[j]);
            float2 ag = __half22float2(h2bits(w[j]));
            o[2 * j] = fmaf(ag.x, di, fmaf(t.x, d2, bb[2 * j]));
            o[2 * j + 1] = fmaf(ag.y, di, fmaf(t.y, d2, bb[2 * j + 1]));
        }
        float4* ov = reinterpret_cast<float4*>(out + (size_t)node * F_OUT);
        ov[m * 2] = make_float4(o[0], o[1], o[2], o[3]);
        ov[m * 2 + 1] = make_float4(o[4], o[5], o[6], o[7]);
    }
}

extern "C" void kernel_launch(void* const* d_in, const int* in_sizes, int n_in,
                              void* d_out, int out_size, void* d_ws,
                              size_t ws_size, hipStream_t stream) {
    const void* edges = d_in[0];
    const float* feat = (const float*)d_in[1];
    const float* loc = (const float*)d_in[2];
    const float* W1 = (const float*)d_in[3];
    const float* b1 = (const float*)d_in[4];
    const float* W2 = (const float*)d_in[5];
    const float* b2 = (const float*)d_in[6];
    float* out = (float*)d_out;

    char* ws = (char*)d_ws;
    float* dinv = (float*)(ws + 0);                //    400,000
    int* rowptr = (int*)(ws + 400000);             //    400,016
    int* src32 = (int*)(ws + 800016);              //  5,000,000
    int* dst32 = (int*)(ws + 5800016);             //  5,000,000
    int* bhist = (int*)(ws + 10800016);            //    156,400
    int* bsum = (int*)(ws + 10956416);             //        256
    unsigned* binned = (unsigned*)(ws + 10956672); //  5,000,000
    unsigned* csr4 = (unsigned*)(ws + 15956672);   //  5,000,000
    __half* x1h = (__half*)(ws + 20956672);        // 12,800,000
    __half* h1a = (__half*)(ws + 33756672);        //  6,400,000
    __half* h1b = (__half*)(ws + 40156672);        //  3,200,000
    __half* h2a = (__half*)(ws + 43356672);        //  6,400,000
    __half* h2b = (__half*)(ws + 49756672);        //  6,400,000
    __half* wpk1 = (__half*)(ws + 56156672);       //      6,144
    __half* wpk2 = (__half*)(ws + 56162816);       //      8,192
    int* flag = (int*)(ws + 56171008);             //          4

    k_misc<<<3, 256, 0, stream>>>((const unsigned*)edges, flag, W1, wpk1, W2,
                                  wpk2);

    // ---- CSR build: scatter-free two-level counting sort ----
    k_prepA<<<NB_BIN, 1024, 0, stream>>>(edges, flag, src32, dst32, bhist);
    k_gscan_part<<<NSCAN_PARTS, 256, 0, stream>>>(bhist, bsum, NSCAN);
    k_gscan_top<<<1, 64, 0, stream>>>(bsum, NSCAN_PARTS);
    k_gscan_down<<<NSCAN_PARTS, 256, 0, stream>>>(bhist, bsum, NSCAN);
    k_place<<<NB_BIN, 1024, 0, stream>>>(src32, dst32, bhist, binned);
    k_bucket<<<NBUK, 256, 0, stream>>>(binned, bhist, dinv, rowptr, csr4);
    k_coef<<<(N_EDGES / 4 + 255) / 256, 256, 0, stream>>>(csr4, dinv);

    // ---- GEMMs + aggregations ----
    int gblocks = (N_NODES / 32 + 3) / 4;  // 782
    k_gemm1<<<gblocks, 256, 0, stream>>>(feat, loc, wpk1, h1a, h1b);
    k_agg1<<<(N_NODES + 3) / 4, 256, 0, stream>>>(h1a, h1b, dinv, rowptr,
                                                  csr4, loc, b1, x1h);
    k_gemm2<<<gblocks, 256, 0, stream>>>(x1h, wpk2, h2a, h2b);
    k_out<<<(N_NODES + 3) / 4, 256, 0, stream>>>(h2a, h2b, dinv, rowptr, csr4,
                                                 b2, out);
}

// Round 13
// 164.734 us; speedup vs baseline: 1.1992x; 1.1992x over previous
//
#include <hip/hip_runtime.h>
#include <hip/hip_fp16.h>

#define N_NODES 100000
#define N_EDGES 1250000
#define F_RAW 48
#define F_LOC 16
#define F1 48
#define F_OUT 64

#define NBUK 391        // ceil(N_NODES/256) dst buckets
#define PADB 4096       // per-bucket padded capacity (mean 3200, +16 sigma)
#define NB2 500         // edge chunks
#define CH2 (N_EDGES / NB2)  // 2500

typedef _Float16 half8_t __attribute__((ext_vector_type(8)));
typedef float floatx4 __attribute__((ext_vector_type(4)));

// ---------------------------------------------------------------------------
// misc: block0 = edge dtype detect; block1/2 = W pack; block3 = cursor init
// ---------------------------------------------------------------------------
__device__ void wprep_dev(const float* W, __half* Wpk, int M, int CT) {
    int lane = threadIdx.x;
    if (lane >= 64) return;
    for (int ct = 0; ct < CT; ++ct)
        for (int kt = 0; kt < 2; ++kt)
            for (int j = 0; j < 8; ++j) {
                int k = kt * 32 + (lane >> 4) * 8 + j;
                int c = ct * 16 + (lane & 15);
                Wpk[((ct * 2 + kt) * 64 + lane) * 8 + j] =
                    __float2half(W[k * M + c]);
            }
}

__global__ void k_misc(const unsigned* edges_u32, int* flag,
                       const float* W1, __half* wpk1,
                       const float* W2, __half* wpk2, int* cursor) {
    if (blockIdx.x == 1) {
        wprep_dev(W1, wpk1, F1, 3);
        return;
    }
    if (blockIdx.x == 2) {
        wprep_dev(W2, wpk2, F_OUT, 4);
        return;
    }
    if (blockIdx.x == 3) {
        for (int k = threadIdx.x; k < NBUK; k += 256) cursor[k] = k * PADB;
        return;
    }
    __shared__ int any;
    if (threadIdx.x == 0) any = 0;
    __syncthreads();
    int nz = 0;
    for (int i = threadIdx.x; i < 2048; i += 256) {
        if (edges_u32[2 * i + 1] != 0u) nz = 1;
    }
    if (nz) atomicOr(&any, 1);
    __syncthreads();
    if (threadIdx.x == 0) *flag = any;
}

__device__ __forceinline__ void load_edge(const void* edges, int is32, int e,
                                          int& s, int& d) {
    if (is32) {
        const int* p = (const int*)edges;
        s = p[e];
        d = p[N_EDGES + e];
    } else {
        const long long* p = (const long long*)edges;
        s = (int)p[e];
        d = (int)p[N_EDGES + e];
    }
}

// ---------------------------------------------------------------------------
// prep2: one pass over edges. LDS hist -> block reservation via one global
// atomicAdd per (block,bucket) -> LDS-stashed edges written to bucket regions.
// binned entry = (dstlocal << 17) | src
// ---------------------------------------------------------------------------
__global__ __launch_bounds__(512) void k_prep2(const void* edges,
                                               const int* flag,
                                               int* __restrict__ cursor,
                                               unsigned* __restrict__ binned) {
    __shared__ int hist[NBUK];
    __shared__ int2 stash[CH2];  // {bucket, entry} 20 KB
    int b = blockIdx.x, t = threadIdx.x;
    for (int k = t; k < NBUK; k += 512) hist[k] = 0;
    __syncthreads();
    int is32 = *flag;
    int e0 = b * CH2;
    for (int i = t; i < CH2; i += 512) {
        int s, d;
        load_edge(edges, is32, e0 + i, s, d);
        int bk = d >> 8;
        stash[i] = make_int2(bk, ((d & 255) << 17) | s);
        atomicAdd(&hist[bk], 1);
    }
    __syncthreads();
    for (int k = t; k < NBUK; k += 512) {
        int c = hist[k];
        hist[k] = c ? atomicAdd(&cursor[k], c) : 0;
    }
    __syncthreads();
    for (int i = t; i < CH2; i += 512) {
        int2 sd = stash[i];
        int p = atomicAdd(&hist[sd.x], 1);
        binned[p] = (unsigned)sd.y;
    }
}

// ---------------------------------------------------------------------------
// bucket: one block per bucket (256 nodes): dinv + rowse{start,end} +
// node-ordered csr4 within the bucket's padded region.
// ---------------------------------------------------------------------------
__global__ __launch_bounds__(256) void k_bucket(
    const unsigned* __restrict__ binned, const int* __restrict__ cursor,
    float* __restrict__ dinv, int2* __restrict__ rowse,
    unsigned* __restrict__ csr4) {
    int k = blockIdx.x, t = threadIdx.x;
    int lane = t & 63, wv = t >> 6;
    __shared__ int ldeg[256];
    __shared__ int wcnt[256];
    __shared__ int ws4[4];
    int base = k * PADB;
    int len = cursor[k] - base;
    ldeg[t] = 0;
    __syncthreads();
    for (int i = t; i < len; i += 256)
        atomicAdd(&ldeg[binned[base + i] >> 17], 1);
    __syncthreads();
    int degv = ldeg[t];
    int x = degv;
#pragma unroll
    for (int off = 1; off < 64; off <<= 1) {
        int u = __shfl_up(x, off);
        if (lane >= off) x += u;
    }
    if (lane == 63) ws4[wv] = x;
    __syncthreads();
    int woff = 0;
    for (int w = 0; w < wv; ++w) woff += ws4[w];
    int excl = woff + x - degv;
    int node = k * 256 + t;
    if (node < N_NODES) {
        dinv[node] = rsqrtf((float)degv + 1.0f);
        rowse[node] = make_int2(base + excl, base + excl + degv);
    }
    wcnt[t] = base + excl;
    __syncthreads();
    for (int i = t; i < len; i += 256) {
        unsigned ent = binned[base + i];
        int p = atomicAdd(&wcnt[ent >> 17], 1);
        csr4[p] = ent & 0x1FFFFu;
    }
}

// ---------------------------------------------------------------------------
// coef: per bucket, stamp csr4[i] = (src<<14) | fp16bits(dinv[src]).
// ---------------------------------------------------------------------------
__global__ __launch_bounds__(256) void k_coef(unsigned* __restrict__ csr4,
                                              const float* __restrict__ dinv,
                                              const int* __restrict__ cursor) {
    int k = blockIdx.x;
    int end = cursor[k];
    for (int i = k * PADB + threadIdx.x; i < end; i += 256) {
        unsigned s = csr4[i];
        csr4[i] = (s << 14) | (unsigned)__half_as_ushort(__float2half(dinv[s]));
    }
}

// ---------------------------------------------------------------------------
// GEMM1: h1 = concat(feat,loc) @ W1, fp32 inputs read directly (cvt in reg).
// 32 nodes/wave, 3 col tiles, K=64; zero-pads h1 cols 48..63 (128B rows).
// ---------------------------------------------------------------------------
__global__ __launch_bounds__(256) void k_gemm1(const float* __restrict__ feat,
                                               const float* __restrict__ loc,
                                               const __half* __restrict__ Wpk,
                                               __half* __restrict__ Y) {
    int wid = threadIdx.x >> 6;
    int lane = threadIdx.x & 63;
    int nb = (blockIdx.x * 4 + wid) * 32;
    if (nb >= N_NODES) return;
    half8_t b[3][2];
#pragma unroll
    for (int ct = 0; ct < 3; ++ct)
#pragma unroll
        for (int kt = 0; kt < 2; ++kt)
            b[ct][kt] = *reinterpret_cast<const half8_t*>(
                Wpk + ((ct * 2 + kt) * 64 + lane) * 8);
    int r = lane & 15;
    int slot = lane >> 4;
    half8_t a[2][2];
#pragma unroll
    for (int rt = 0; rt < 2; ++rt)
#pragma unroll
        for (int kt = 0; kt < 2; ++kt) {
            int sl = kt * 4 + slot;
            int node = nb + rt * 16 + r;
            const float* sp = (sl < 6)
                                  ? feat + (size_t)node * F_RAW + sl * 8
                                  : loc + (size_t)node * F_LOC + (sl - 6) * 8;
            float4 f0 = reinterpret_cast<const float4*>(sp)[0];
            float4 f1 = reinterpret_cast<const float4*>(sp)[1];
            half8_t h;
            h[0] = (_Float16)f0.x;
            h[1] = (_Float16)f0.y;
            h[2] = (_Float16)f0.z;
            h[3] = (_Float16)f0.w;
            h[4] = (_Float16)f1.x;
            h[5] = (_Float16)f1.y;
            h[6] = (_Float16)f1.z;
            h[7] = (_Float16)f1.w;
            a[rt][kt] = h;
        }
    floatx4 acc[2][3];
#pragma unroll
    for (int rt = 0; rt < 2; ++rt)
#pragma unroll
        for (int ct = 0; ct < 3; ++ct) {
            floatx4 z = {0.f, 0.f, 0.f, 0.f};
            z = __builtin_amdgcn_mfma_f32_16x16x32_f16(a[rt][0], b[ct][0], z, 0, 0, 0);
            z = __builtin_amdgcn_mfma_f32_16x16x32_f16(a[rt][1], b[ct][1], z, 0, 0, 0);
            acc[rt][ct] = z;
        }
    int row0 = (lane >> 4) * 4;
    int col = lane & 15;
#pragma unroll
    for (int rt = 0; rt < 2; ++rt)
#pragma unroll
        for (int ct = 0; ct < 3; ++ct)
#pragma unroll
            for (int j = 0; j < 4; ++j) {
                int node = nb + rt * 16 + row0 + j;
                Y[(size_t)node * 64 + ct * 16 + col] = __float2half(acc[rt][ct][j]);
            }
    int node = nb + (lane & 31);
    int slotp = 6 + (lane >> 5);
    *reinterpret_cast<int4*>(Y + (size_t)node * 64 + slotp * 8) =
        make_int4(0, 0, 0, 0);
}

// ---------------------------------------------------------------------------
// GEMM2: h2 = x1 @ W2 (fp16 in), unified 128B rows out.
// ---------------------------------------------------------------------------
__global__ __launch_bounds__(256) void k_gemm2(const __half* __restrict__ X,
                                               const __half* __restrict__ Wpk,
                                               __half* __restrict__ Y) {
    int wid = threadIdx.x >> 6;
    int lane = threadIdx.x & 63;
    int nb = (blockIdx.x * 4 + wid) * 32;
    if (nb >= N_NODES) return;
    half8_t b[4][2];
#pragma unroll
    for (int ct = 0; ct < 4; ++ct)
#pragma unroll
        for (int kt = 0; kt < 2; ++kt)
            b[ct][kt] = *reinterpret_cast<const half8_t*>(
                Wpk + ((ct * 2 + kt) * 64 + lane) * 8);
    int r = lane & 15;
    int ks = (lane >> 4) * 8;
    half8_t a[2][2];
#pragma unroll
    for (int rt = 0; rt < 2; ++rt)
#pragma unroll
        for (int kt = 0; kt < 2; ++kt)
            a[rt][kt] = *reinterpret_cast<const half8_t*>(
                X + ((size_t)(nb + rt * 16 + r) * 64 + kt * 32 + ks));
    floatx4 acc[2][4];
#pragma unroll
    for (int rt = 0; rt < 2; ++rt)
#pragma unroll
        for (int ct = 0; ct < 4; ++ct) {
            floatx4 z = {0.f, 0.f, 0.f, 0.f};
            z = __builtin_amdgcn_mfma_f32_16x16x32_f16(a[rt][0], b[ct][0], z, 0, 0, 0);
            z = __builtin_amdgcn_mfma_f32_16x16x32_f16(a[rt][1], b[ct][1], z, 0, 0, 0);
            acc[rt][ct] = z;
        }
    int row0 = (lane >> 4) * 4;
    int col = lane & 15;
#pragma unroll
    for (int rt = 0; rt < 2; ++rt)
#pragma unroll
        for (int ct = 0; ct < 4; ++ct)
#pragma unroll
            for (int j = 0; j < 4; ++j) {
                int node = nb + rt * 16 + row0 + j;
                Y[(size_t)node * 64 + ct * 16 + col] = __float2half(acc[rt][ct][j]);
            }
}

// ---------------------------------------------------------------------------
// gather helpers: fp16 packed accumulate
// ---------------------------------------------------------------------------
__device__ __forceinline__ __half2 c2_from(unsigned A) {
    unsigned b = A & 0x3FFFu;
    unsigned p = b | (b << 16);
    return *reinterpret_cast<__half2*>(&p);
}

__device__ __forceinline__ void fma8h(const int4& p, __half2 c2, __half2 a[4]) {
    const __half2* h = reinterpret_cast<const __half2*>(&p);
#pragma unroll
    for (int j = 0; j < 4; ++j) a[j] = __hfma2(h[j], c2, a[j]);
}

__device__ __forceinline__ __half2 shfl_xor_h2(__half2 v, int m) {
    int i = *reinterpret_cast<int*>(&v);
    i = __shfl_xor(i, m);
    return *reinterpret_cast<__half2*>(&i);
}

// agg1: x1 = [relu(agg(h1)*di + h1*d2 + b1) (48) | loc (16)] as fp16 rows
__global__ __launch_bounds__(256) void k_agg1(
    const __half* __restrict__ h1h, const float* __restrict__ dinv,
    const int2* __restrict__ rowse, const unsigned* __restrict__ csr4,
    const float* __restrict__ loc, const float* __restrict__ b1,
    __half* __restrict__ x1h) {
    int wave = threadIdx.x >> 6;
    int lane = threadIdx.x & 63;
    int grp = lane >> 3;
    int l8 = lane & 7;
    int node = blockIdx.x * 4 + wave;
    if (node >= N_NODES) return;
    int2 se = rowse[node];
    int r0 = se.x, r1 = se.y;
    const char* h1l = reinterpret_cast<const char*>(h1h) + (l8 << 4);
    float di = dinv[node];
    int4 hs = *reinterpret_cast<const int4*>(h1l + ((size_t)node << 7));
    int len = r1 - r0;
    int L = (len + 7) >> 3;
    int gs = r0 + grp * L;
    int ge = gs + L;
    if (ge > r1) ge = r1;
    __half2 z2 = __float2half2_rn(0.f);
    __half2 a0[4] = {z2, z2, z2, z2};
    __half2 a1[4] = {z2, z2, z2, z2};
    int e = gs;
    for (; e + 1 < ge; e += 2) {
        unsigned A = csr4[e];
        unsigned B = csr4[e + 1];
        int4 vA = *reinterpret_cast<const int4*>(h1l + ((A >> 14) << 7));
        int4 vB = *reinterpret_cast<const int4*>(h1l + ((B >> 14) << 7));
        fma8h(vA, c2_from(A), a0);
        fma8h(vB, c2_from(B), a1);
    }
    if (e < ge) {
        unsigned A = csr4[e];
        int4 vA = *reinterpret_cast<const int4*>(h1l + ((A >> 14) << 7));
        fma8h(vA, c2_from(A), a0);
    }
#pragma unroll
    for (int j = 0; j < 4; ++j) a0[j] = __hadd2(a0[j], a1[j]);
#pragma unroll
    for (int j = 0; j < 4; ++j) {
        a0[j] = __hadd2(a0[j], shfl_xor_h2(a0[j], 8));
        a0[j] = __hadd2(a0[j], shfl_xor_h2(a0[j], 16));
        a0[j] = __hadd2(a0[j], shfl_xor_h2(a0[j], 32));
    }
    if (lane < 8) {
        __half2 q[4];
        if (l8 < 6) {
            float d2 = di * di;
            const float4* b1v = reinterpret_cast<const float4*>(b1);
            float4 bA = b1v[l8 * 2];
            float4 bB = b1v[l8 * 2 + 1];
            float bb[8] = {bA.x, bA.y, bA.z, bA.w, bB.x, bB.y, bB.z, bB.w};
            const __half2* hh = reinterpret_cast<const __half2*>(&hs);
            float o[8];
#pragma unroll
            for (int j = 0; j < 4; ++j) {
                float2 t = __half22float2(hh[j]);
                float2 ag = __half22float2(a0[j]);
                o[2 * j] = fmaxf(fmaf(ag.x, di, fmaf(t.x, d2, bb[2 * j])), 0.f);
                o[2 * j + 1] =
                    fmaxf(fmaf(ag.y, di, fmaf(t.y, d2, bb[2 * j + 1])), 0.f);
            }
#pragma unroll
            for (int j = 0; j < 4; ++j)
                q[j] = __halves2half2(__float2half(o[2 * j]),
                                      __float2half(o[2 * j + 1]));
        } else {
            const float* lp = loc + (size_t)node * F_LOC + (l8 - 6) * 8;
            float4 f0 = reinterpret_cast<const float4*>(lp)[0];
            float4 f1 = reinterpret_cast<const float4*>(lp)[1];
            q[0] = __halves2half2(__float2half(f0.x), __float2half(f0.y));
            q[1] = __halves2half2(__float2half(f0.z), __float2half(f0.w));
            q[2] = __halves2half2(__float2half(f1.x), __float2half(f1.y));
            q[3] = __halves2half2(__float2half(f1.z), __float2half(f1.w));
        }
        reinterpret_cast<int4*>(x1h)[(size_t)node * 8 + l8] =
            *reinterpret_cast<int4*>(q);
    }
}

// agg2 + self + bias -> out (fp32)
__global__ __launch_bounds__(256) void k_out(
    const __half* __restrict__ h2h, const float* __restrict__ dinv,
    const int2* __restrict__ rowse, const unsigned* __restrict__ csr4,
    const float* __restrict__ b2, float* __restrict__ out) {
    int wave = threadIdx.x >> 6;
    int lane = threadIdx.x & 63;
    int grp = lane >> 3;
    int l8 = lane & 7;
    int node = blockIdx.x * 4 + wave;
    if (node >= N_NODES) return;
    int2 se = rowse[node];
    int r0 = se.x, r1 = se.y;
    const char* h2l = reinterpret_cast<const char*>(h2h) + (l8 << 4);
    float di = dinv[node];
    int4 hs = *reinterpret_cast<const int4*>(h2l + ((size_t)node << 7));
    int len = r1 - r0;
    int L = (len + 7) >> 3;
    int gs = r0 + grp * L;
    int ge = gs + L;
    if (ge > r1) ge = r1;
    __half2 z2 = __float2half2_rn(0.f);
    __half2 a0[4] = {z2, z2, z2, z2};
    __half2 a1[4] = {z2, z2, z2, z2};
    int e = gs;
    for (; e + 1 < ge; e += 2) {
        unsigned A = csr4[e];
        unsigned B = csr4[e + 1];
        int4 vA = *reinterpret_cast<const int4*>(h2l + ((A >> 14) << 7));
        int4 vB = *reinterpret_cast<const int4*>(h2l + ((B >> 14) << 7));
        fma8h(vA, c2_from(A), a0);
        fma8h(vB, c2_from(B), a1);
    }
    if (e < ge) {
        unsigned A = csr4[e];
        int4 vA = *reinterpret_cast<const int4*>(h2l + ((A >> 14) << 7));
        fma8h(vA, c2_from(A), a0);
    }
#pragma unroll
    for (int j = 0; j < 4; ++j) a0[j] = __hadd2(a0[j], a1[j]);
#pragma unroll
    for (int j = 0; j < 4; ++j) {
        a0[j] = __hadd2(a0[j], shfl_xor_h2(a0[j], 8));
        a0[j] = __hadd2(a0[j], shfl_xor_h2(a0[j], 16));
        a0[j] = __hadd2(a0[j], shfl_xor_h2(a0[j], 32));
    }
    if (lane < 8) {
        float d2 = di * di;
        const float4* b2v = reinterpret_cast<const float4*>(b2);
        float4 bA = b2v[l8 * 2];
        float4 bB = b2v[l8 * 2 + 1];
        float bb[8] = {bA.x, bA.y, bA.z, bA.w, bB.x, bB.y, bB.z, bB.w};
        const __half2* hh = reinterpret_cast<const __half2*>(&hs);
        float o[8];
#pragma unroll
        for (int j = 0; j < 4; ++j) {
            float2 t = __half22float2(hh[j]);
            float2 ag = __half22float2(a0[j]);
            o[2 * j] = fmaf(ag.x, di, fmaf(t.x, d2, bb[2 * j]));
            o[2 * j + 1] = fmaf(ag.y, di, fmaf(t.y, d2, bb[2 * j + 1]));
        }
        float4* ov = reinterpret_cast<float4*>(out + (size_t)node * F_OUT);
        ov[l8 * 2] = make_float4(o[0], o[1], o[2], o[3]);
        ov[l8 * 2 + 1] = make_float4(o[4], o[5], o[6], o[7]);
    }
}

extern "C" void kernel_launch(void* const* d_in, const int* in_sizes, int n_in,
                              void* d_out, int out_size, void* d_ws,
                              size_t ws_size, hipStream_t stream) {
    const void* edges = d_in[0];
    const float* feat = (const float*)d_in[1];
    const float* loc = (const float*)d_in[2];
    const float* W1 = (const float*)d_in[3];
    const float* b1 = (const float*)d_in[4];
    const float* W2 = (const float*)d_in[5];
    const float* b2 = (const float*)d_in[6];
    float* out = (float*)d_out;

    char* ws = (char*)d_ws;
    float* dinv = (float*)(ws + 0);                //    400,000
    int2* rowse = (int2*)(ws + 400000);            //    800,000
    int* cursor = (int*)(ws + 1200000);            //      1,568
    unsigned* binned = (unsigned*)(ws + 1201568);  //  6,406,144
    unsigned* csr4 = (unsigned*)(ws + 7607712);    //  6,406,144
    __half* h1h = (__half*)(ws + 14013856);        // 12,800,000
    __half* x1h = (__half*)(ws + 26813856);        // 12,800,000
    __half* h2h = (__half*)(ws + 39613856);        // 12,800,000
    __half* wpk1 = (__half*)(ws + 52413856);       //      6,144
    __half* wpk2 = (__half*)(ws + 52420000);       //      8,192
    int* flag = (int*)(ws + 52428192);             //          4

    k_misc<<<4, 256, 0, stream>>>((const unsigned*)edges, flag, W1, wpk1, W2,
                                  wpk2, cursor);

    // ---- CSR build: single-pass binning w/ atomic block reservation ----
    k_prep2<<<NB2, 512, 0, stream>>>(edges, flag, cursor, binned);
    k_bucket<<<NBUK, 256, 0, stream>>>(binned, cursor, dinv, rowse, csr4);
    k_coef<<<NBUK, 256, 0, stream>>>(csr4, dinv, cursor);

    // ---- GEMMs + aggregations ----
    int gblocks = (N_NODES / 32 + 3) / 4;  // 782
    k_gemm1<<<gblocks, 256, 0, stream>>>(feat, loc, wpk1, h1h);
    k_agg1<<<(N_NODES + 3) / 4, 256, 0, stream>>>(h1h, dinv, rowse, csr4, loc,
                                                  b1, x1h);
    k_gemm2<<<gblocks, 256, 0, stream>>>(x1h, wpk2, h2h);
    k_out<<<(N_NODES + 3) / 4, 256, 0, stream>>>(h2h, dinv, rowse, csr4, b2,
                                                 out);
}

// Round 14
// 149.900 us; speedup vs baseline: 1.3179x; 1.0990x over previous
//
#include <hip/hip_runtime.h>
#include <hip/hip_fp16.h>

#define N_NODES 100000
#define N_EDGES 1250000
#define F_RAW 48
#define F_LOC 16
#define F1 48
#define F_OUT 64

#define NBUK 391             // ceil(N_NODES/256) dst buckets
#define PADB 4096            // per-bucket padded capacity (mean 3200, +16 sigma)
#define NB2 500              // edge chunks
#define CH2 (N_EDGES / NB2)  // 2500

typedef _Float16 half8_t __attribute__((ext_vector_type(8)));
typedef float floatx4 __attribute__((ext_vector_type(4)));

// ---------------------------------------------------------------------------
// W pack: Wpk[((ct*2+kt)*64+lane)*8+j] = W[kt*32+(lane>>4)*8+j][ct*16+(lane&15)]
// ---------------------------------------------------------------------------
__device__ void wprep_dev(const float* W, __half* Wpk, int M, int CT) {
    int lane = threadIdx.x;
    if (lane >= 64) return;
    for (int ct = 0; ct < CT; ++ct)
        for (int kt = 0; kt < 2; ++kt)
            for (int j = 0; j < 8; ++j) {
                int k = kt * 32 + (lane >> 4) * 8 + j;
                int c = ct * 16 + (lane & 15);
                Wpk[((ct * 2 + kt) * 64 + lane) * 8 + j] =
                    __float2half(W[k * M + c]);
            }
}

__device__ __forceinline__ void load_edge(const void* edges, int is32, int e,
                                          int& s, int& d) {
    if (is32) {
        const int* p = (const int*)edges;
        s = p[e];
        d = p[N_EDGES + e];
    } else {
        const long long* p = (const long long*)edges;
        s = (int)p[e];
        d = (int)p[N_EDGES + e];
    }
}

// ---------------------------------------------------------------------------
// prep2: blocks 0..499 = edge binning (per-block dtype detect, LDS hist,
// atomic block reservation, LDS-stashed scatter). Blocks 500/501 = W pack.
// binned entry = (dstlocal << 17) | src. cursor[k] counts entries in bucket k.
// ---------------------------------------------------------------------------
__global__ __launch_bounds__(512) void k_prep2(const void* edges,
                                               const float* W1, __half* wpk1,
                                               const float* W2, __half* wpk2,
                                               int* __restrict__ cursor,
                                               unsigned* __restrict__ binned) {
    int b = blockIdx.x, t = threadIdx.x;
    if (b >= NB2) {
        if (b == NB2)
            wprep_dev(W1, wpk1, F1, 3);
        else
            wprep_dev(W2, wpk2, F_OUT, 4);
        return;
    }
    __shared__ int hist[NBUK];
    __shared__ int2 stash[CH2];  // {bucket, entry} 20 KB
    __shared__ int s_any;
    if (t == 0) s_any = 0;
    for (int k = t; k < NBUK; k += 512) hist[k] = 0;
    __syncthreads();
    int e0 = b * CH2;
    // per-block dtype detect: int64 edges < 2^31 have all odd u32 words zero.
    // sample 512 odd words of this chunk's int64-view src range.
    const unsigned* eu = (const unsigned*)edges;
    if (eu[2 * (e0 + t) + 1] != 0u) atomicOr(&s_any, 1);
    __syncthreads();
    int is32 = s_any;  // nonzero odd word => int32 buffer
    for (int i = t; i < CH2; i += 512) {
        int s, d;
        load_edge(edges, is32, e0 + i, s, d);
        int bk = d >> 8;
        stash[i] = make_int2(bk, ((d & 255) << 17) | s);
        atomicAdd(&hist[bk], 1);
    }
    __syncthreads();
    for (int k = t; k < NBUK; k += 512) {
        int c = hist[k];
        hist[k] = (c ? atomicAdd(&cursor[k], c) : 0) + k * PADB;
    }
    __syncthreads();
    for (int i = t; i < CH2; i += 512) {
        int2 sd = stash[i];
        int p = atomicAdd(&hist[sd.x], 1);
        binned[p] = (unsigned)sd.y;
    }
}

// ---------------------------------------------------------------------------
// bucket: one block per bucket (256 nodes): dinv + rowse{start,end} +
// node-ordered csr4 within the bucket's padded region.
// ---------------------------------------------------------------------------
__global__ __launch_bounds__(256) void k_bucket(
    const unsigned* __restrict__ binned, const int* __restrict__ cursor,
    float* __restrict__ dinv, int2* __restrict__ rowse,
    unsigned* __restrict__ csr4) {
    int k = blockIdx.x, t = threadIdx.x;
    int lane = t & 63, wv = t >> 6;
    __shared__ int ldeg[256];
    __shared__ int wcnt[256];
    __shared__ int ws4[4];
    int base = k * PADB;
    int len = cursor[k];
    ldeg[t] = 0;
    __syncthreads();
    for (int i = t; i < len; i += 256)
        atomicAdd(&ldeg[binned[base + i] >> 17], 1);
    __syncthreads();
    int degv = ldeg[t];
    int x = degv;
#pragma unroll
    for (int off = 1; off < 64; off <<= 1) {
        int u = __shfl_up(x, off);
        if (lane >= off) x += u;
    }
    if (lane == 63) ws4[wv] = x;
    __syncthreads();
    int woff = 0;
    for (int w = 0; w < wv; ++w) woff += ws4[w];
    int excl = woff + x - degv;
    int node = k * 256 + t;
    if (node < N_NODES) {
        dinv[node] = rsqrtf((float)degv + 1.0f);
        rowse[node] = make_int2(base + excl, base + excl + degv);
    }
    wcnt[t] = base + excl;
    __syncthreads();
    for (int i = t; i < len; i += 256) {
        unsigned ent = binned[base + i];
        int p = atomicAdd(&wcnt[ent >> 17], 1);
        csr4[p] = ent & 0x1FFFFu;
    }
}

// ---------------------------------------------------------------------------
// coef: per bucket, stamp csr4[i] = (src<<14) | fp16bits(dinv[src]).
// ---------------------------------------------------------------------------
__global__ __launch_bounds__(256) void k_coef(unsigned* __restrict__ csr4,
                                              const float* __restrict__ dinv,
                                              const int* __restrict__ cursor) {
    int k = blockIdx.x;
    int end = k * PADB + cursor[k];
    for (int i = k * PADB + threadIdx.x; i < end; i += 256) {
        unsigned s = csr4[i];
        csr4[i] = (s << 14) | (unsigned)__half_as_ushort(__float2half(dinv[s]));
    }
}

// ---------------------------------------------------------------------------
// GEMM1: h1 = concat(feat,loc) @ W1, fp32 inputs read directly (cvt in reg).
// 32 nodes/wave, 3 col tiles, K=64; zero-pads h1 cols 48..63 (128B rows).
// ---------------------------------------------------------------------------
__global__ __launch_bounds__(256) void k_gemm1(const float* __restrict__ feat,
                                               const float* __restrict__ loc,
                                               const __half* __restrict__ Wpk,
                                               __half* __restrict__ Y) {
    int wid = threadIdx.x >> 6;
    int lane = threadIdx.x & 63;
    int nb = (blockIdx.x * 4 + wid) * 32;
    if (nb >= N_NODES) return;
    half8_t b[3][2];
#pragma unroll
    for (int ct = 0; ct < 3; ++ct)
#pragma unroll
        for (int kt = 0; kt < 2; ++kt)
            b[ct][kt] = *reinterpret_cast<const half8_t*>(
                Wpk + ((ct * 2 + kt) * 64 + lane) * 8);
    int r = lane & 15;
    int slot = lane >> 4;
    half8_t a[2][2];
#pragma unroll
    for (int rt = 0; rt < 2; ++rt)
#pragma unroll
        for (int kt = 0; kt < 2; ++kt) {
            int sl = kt * 4 + slot;
            int node = nb + rt * 16 + r;
            const float* sp = (sl < 6)
                                  ? feat + (size_t)node * F_RAW + sl * 8
                                  : loc + (size_t)node * F_LOC + (sl - 6) * 8;
            float4 f0 = reinterpret_cast<const float4*>(sp)[0];
            float4 f1 = reinterpret_cast<const float4*>(sp)[1];
            half8_t h;
            h[0] = (_Float16)f0.x;
            h[1] = (_Float16)f0.y;
            h[2] = (_Float16)f0.z;
            h[3] = (_Float16)f0.w;
            h[4] = (_Float16)f1.x;
            h[5] = (_Float16)f1.y;
            h[6] = (_Float16)f1.z;
            h[7] = (_Float16)f1.w;
            a[rt][kt] = h;
        }
    floatx4 acc[2][3];
#pragma unroll
    for (int rt = 0; rt < 2; ++rt)
#pragma unroll
        for (int ct = 0; ct < 3; ++ct) {
            floatx4 z = {0.f, 0.f, 0.f, 0.f};
            z = __builtin_amdgcn_mfma_f32_16x16x32_f16(a[rt][0], b[ct][0], z, 0, 0, 0);
            z = __builtin_amdgcn_mfma_f32_16x16x32_f16(a[rt][1], b[ct][1], z, 0, 0, 0);
            acc[rt][ct] = z;
        }
    int row0 = (lane >> 4) * 4;
    int col = lane & 15;
#pragma unroll
    for (int rt = 0; rt < 2; ++rt)
#pragma unroll
        for (int ct = 0; ct < 3; ++ct)
#pragma unroll
            for (int j = 0; j < 4; ++j) {
                int node = nb + rt * 16 + row0 + j;
                Y[(size_t)node * 64 + ct * 16 + col] = __float2half(acc[rt][ct][j]);
            }
    int node = nb + (lane & 31);
    int slotp = 6 + (lane >> 5);
    *reinterpret_cast<int4*>(Y + (size_t)node * 64 + slotp * 8) =
        make_int4(0, 0, 0, 0);
}

// ---------------------------------------------------------------------------
// GEMM2: h2 = x1 @ W2 (fp16 in), 128B rows out.
// ---------------------------------------------------------------------------
__global__ __launch_bounds__(256) void k_gemm2(const __half* __restrict__ X,
                                               const __half* __restrict__ Wpk,
                                               __half* __restrict__ Y) {
    int wid = threadIdx.x >> 6;
    int lane = threadIdx.x & 63;
    int nb = (blockIdx.x * 4 + wid) * 32;
    if (nb >= N_NODES) return;
    half8_t b[4][2];
#pragma unroll
    for (int ct = 0; ct < 4; ++ct)
#pragma unroll
        for (int kt = 0; kt < 2; ++kt)
            b[ct][kt] = *reinterpret_cast<const half8_t*>(
                Wpk + ((ct * 2 + kt) * 64 + lane) * 8);
    int r = lane & 15;
    int ks = (lane >> 4) * 8;
    half8_t a[2][2];
#pragma unroll
    for (int rt = 0; rt < 2; ++rt)
#pragma unroll
        for (int kt = 0; kt < 2; ++kt)
            a[rt][kt] = *reinterpret_cast<const half8_t*>(
                X + ((size_t)(nb + rt * 16 + r) * 64 + kt * 32 + ks));
    floatx4 acc[2][4];
#pragma unroll
    for (int rt = 0; rt < 2; ++rt)
#pragma unroll
        for (int ct = 0; ct < 4; ++ct) {
            floatx4 z = {0.f, 0.f, 0.f, 0.f};
            z = __builtin_amdgcn_mfma_f32_16x16x32_f16(a[rt][0], b[ct][0], z, 0, 0, 0);
            z = __builtin_amdgcn_mfma_f32_16x16x32_f16(a[rt][1], b[ct][1], z, 0, 0, 0);
            acc[rt][ct] = z;
        }
    int row0 = (lane >> 4) * 4;
    int col = lane & 15;
#pragma unroll
    for (int rt = 0; rt < 2; ++rt)
#pragma unroll
        for (int ct = 0; ct < 4; ++ct)
#pragma unroll
            for (int j = 0; j < 4; ++j) {
                int node = nb + rt * 16 + row0 + j;
                Y[(size_t)node * 64 + ct * 16 + col] = __float2half(acc[rt][ct][j]);
            }
}

// ---------------------------------------------------------------------------
// gather helpers: fp16 packed accumulate
// ---------------------------------------------------------------------------
__device__ __forceinline__ __half2 c2_from(unsigned A) {
    unsigned b = A & 0x3FFFu;
    unsigned p = b | (b << 16);
    return *reinterpret_cast<__half2*>(&p);
}

__device__ __forceinline__ void fma8h(const int4& p, __half2 c2, __half2 a[4]) {
    const __half2* h = reinterpret_cast<const __half2*>(&p);
#pragma unroll
    for (int j = 0; j < 4; ++j) a[j] = __hfma2(h[j], c2, a[j]);
}

__device__ __forceinline__ __half2 shfl_xor_h2(__half2 v, int m) {
    int i = *reinterpret_cast<int*>(&v);
    i = __shfl_xor(i, m);
    return *reinterpret_cast<__half2*>(&i);
}

// agg1: x1 = [relu(agg(h1)*di + h1*d2 + b1) (48) | loc (16)] as fp16 rows
__global__ __launch_bounds__(256) void k_agg1(
    const __half* __restrict__ h1h, const float* __restrict__ dinv,
    const int2* __restrict__ rowse, const unsigned* __restrict__ csr4,
    const float* __restrict__ loc, const float* __restrict__ b1,
    __half* __restrict__ x1h) {
    int wave = threadIdx.x >> 6;
    int lane = threadIdx.x & 63;
    int grp = lane >> 3;
    int l8 = lane & 7;
    int node = blockIdx.x * 4 + wave;
    if (node >= N_NODES) return;
    int2 se = rowse[node];
    int r0 = se.x, r1 = se.y;
    const char* h1l = reinterpret_cast<const char*>(h1h) + (l8 << 4);
    float di = dinv[node];
    int4 hs = *reinterpret_cast<const int4*>(h1l + ((size_t)node << 7));
    int len = r1 - r0;
    int L = (len + 7) >> 3;
    int gs = r0 + grp * L;
    int ge = gs + L;
    if (ge > r1) ge = r1;
    __half2 z2 = __float2half2_rn(0.f);
    __half2 a0[4] = {z2, z2, z2, z2};
    __half2 a1[4] = {z2, z2, z2, z2};
    int e = gs;
    for (; e + 1 < ge; e += 2) {
        unsigned A = csr4[e];
        unsigned B = csr4[e + 1];
        int4 vA = *reinterpret_cast<const int4*>(h1l + ((A >> 14) << 7));
        int4 vB = *reinterpret_cast<const int4*>(h1l + ((B >> 14) << 7));
        fma8h(vA, c2_from(A), a0);
        fma8h(vB, c2_from(B), a1);
    }
    if (e < ge) {
        unsigned A = csr4[e];
        int4 vA = *reinterpret_cast<const int4*>(h1l + ((A >> 14) << 7));
        fma8h(vA, c2_from(A), a0);
    }
#pragma unroll
    for (int j = 0; j < 4; ++j) a0[j] = __hadd2(a0[j], a1[j]);
#pragma unroll
    for (int j = 0; j < 4; ++j) {
        a0[j] = __hadd2(a0[j], shfl_xor_h2(a0[j], 8));
        a0[j] = __hadd2(a0[j], shfl_xor_h2(a0[j], 16));
        a0[j] = __hadd2(a0[j], shfl_xor_h2(a0[j], 32));
    }
    if (lane < 8) {
        __half2 q[4];
        if (l8 < 6) {
            float d2 = di * di;
            const float4* b1v = reinterpret_cast<const float4*>(b1);
            float4 bA = b1v[l8 * 2];
            float4 bB = b1v[l8 * 2 + 1];
            float bb[8] = {bA.x, bA.y, bA.z, bA.w, bB.x, bB.y, bB.z, bB.w};
            const __half2* hh = reinterpret_cast<const __half2*>(&hs);
            float o[8];
#pragma unroll
            for (int j = 0; j < 4; ++j) {
                float2 t = __half22float2(hh[j]);
                float2 ag = __half22float2(a0[j]);
                o[2 * j] = fmaxf(fmaf(ag.x, di, fmaf(t.x, d2, bb[2 * j])), 0.f);
                o[2 * j + 1] =
                    fmaxf(fmaf(ag.y, di, fmaf(t.y, d2, bb[2 * j + 1])), 0.f);
            }
#pragma unroll
            for (int j = 0; j < 4; ++j)
                q[j] = __halves2half2(__float2half(o[2 * j]),
                                      __float2half(o[2 * j + 1]));
        } else {
            const float* lp = loc + (size_t)node * F_LOC + (l8 - 6) * 8;
            float4 f0 = reinterpret_cast<const float4*>(lp)[0];
            float4 f1 = reinterpret_cast<const float4*>(lp)[1];
            q[0] = __halves2half2(__float2half(f0.x), __float2half(f0.y));
            q[1] = __halves2half2(__float2half(f0.z), __float2half(f0.w));
            q[2] = __halves2half2(__float2half(f1.x), __float2half(f1.y));
            q[3] = __halves2half2(__float2half(f1.z), __float2half(f1.w));
        }
        reinterpret_cast<int4*>(x1h)[(size_t)node * 8 + l8] =
            *reinterpret_cast<int4*>(q);
    }
}

// agg2 + self + bias -> out (fp32)
__global__ __launch_bounds__(256) void k_out(
    const __half* __restrict__ h2h, const float* __restrict__ dinv,
    const int2* __restrict__ rowse, const unsigned* __restrict__ csr4,
    const float* __restrict__ b2, float* __restrict__ out) {
    int wave = threadIdx.x >> 6;
    int lane = threadIdx.x & 63;
    int grp = lane >> 3;
    int l8 = lane & 7;
    int node = blockIdx.x * 4 + wave;
    if (node >= N_NODES) return;
    int2 se = rowse[node];
    int r0 = se.x, r1 = se.y;
    const char* h2l = reinterpret_cast<const char*>(h2h) + (l8 << 4);
    float di = dinv[node];
    int4 hs = *reinterpret_cast<const int4*>(h2l + ((size_t)node << 7));
    int len = r1 - r0;
    int L = (len + 7) >> 3;
    int gs = r0 + grp * L;
    int ge = gs + L;
    if (ge > r1) ge = r1;
    __half2 z2 = __float2half2_rn(0.f);
    __half2 a0[4] = {z2, z2, z2, z2};
    __half2 a1[4] = {z2, z2, z2, z2};
    int e = gs;
    for (; e + 1 < ge; e += 2) {
        unsigned A = csr4[e];
        unsigned B = csr4[e + 1];
        int4 vA = *reinterpret_cast<const int4*>(h2l + ((A >> 14) << 7));
        int4 vB = *reinterpret_cast<const int4*>(h2l + ((B >> 14) << 7));
        fma8h(vA, c2_from(A), a0);
        fma8h(vB, c2_from(B), a1);
    }
    if (e < ge) {
        unsigned A = csr4[e];
        int4 vA = *reinterpret_cast<const int4*>(h2l + ((A >> 14) << 7));
        fma8h(vA, c2_from(A), a0);
    }
#pragma unroll
    for (int j = 0; j < 4; ++j) a0[j] = __hadd2(a0[j], a1[j]);
#pragma unroll
    for (int j = 0; j < 4; ++j) {
        a0[j] = __hadd2(a0[j], shfl_xor_h2(a0[j], 8));
        a0[j] = __hadd2(a0[j], shfl_xor_h2(a0[j], 16));
        a0[j] = __hadd2(a0[j], shfl_xor_h2(a0[j], 32));
    }
    if (lane < 8) {
        float d2 = di * di;
        const float4* b2v = reinterpret_cast<const float4*>(b2);
        float4 bA = b2v[l8 * 2];
        float4 bB = b2v[l8 * 2 + 1];
        float bb[8] = {bA.x, bA.y, bA.z, bA.w, bB.x, bB.y, bB.z, bB.w};
        const __half2* hh = reinterpret_cast<const __half2*>(&hs);
        float o[8];
#pragma unroll
        for (int j = 0; j < 4; ++j) {
            float2 t = __half22float2(hh[j]);
            float2 ag = __half22float2(a0[j]);
            o[2 * j] = fmaf(ag.x, di, fmaf(t.x, d2, bb[2 * j]));
            o[2 * j + 1] = fmaf(ag.y, di, fmaf(t.y, d2, bb[2 * j + 1]));
        }
        float4* ov = reinterpret_cast<float4*>(out + (size_t)node * F_OUT);
        ov[l8 * 2] = make_float4(o[0], o[1], o[2], o[3]);
        ov[l8 * 2 + 1] = make_float4(o[4], o[5], o[6], o[7]);
    }
}

extern "C" void kernel_launch(void* const* d_in, const int* in_sizes, int n_in,
                              void* d_out, int out_size, void* d_ws,
                              size_t ws_size, hipStream_t stream) {
    const void* edges = d_in[0];
    const float* feat = (const float*)d_in[1];
    const float* loc = (const float*)d_in[2];
    const float* W1 = (const float*)d_in[3];
    const float* b1 = (const float*)d_in[4];
    const float* W2 = (const float*)d_in[5];
    const float* b2 = (const float*)d_in[6];
    float* out = (float*)d_out;

    // All offsets multiples of 128 (h1h/x1h/h2h rows are 128B — alignment is
    // perf-critical: r13's 32-mod-128 base cost +50% gather fetch).
    char* ws = (char*)d_ws;
    float* dinv = (float*)(ws + 0);                //    400,000
    int2* rowse = (int2*)(ws + 400000);            //    800,000
    int* cursor = (int*)(ws + 1200000);            //      1,664 (pad)
    unsigned* binned = (unsigned*)(ws + 1201664);  //  6,406,144
    unsigned* csr4 = (unsigned*)(ws + 7607808);    //  6,406,144
    __half* h1h = (__half*)(ws + 14013952);        // 12,800,000
    __half* x1h = (__half*)(ws + 26813952);        // 12,800,000
    __half* h2h = (__half*)(ws + 39613952);        // 12,800,000
    __half* wpk1 = (__half*)(ws + 52413952);       //      6,144
    __half* wpk2 = (__half*)(ws + 52420096);       //      8,192

    hipMemsetAsync(cursor, 0, NBUK * 4, stream);

    // ---- CSR build: single-pass binning + W pack (fused grid) ----
    k_prep2<<<NB2 + 2, 512, 0, stream>>>(edges, W1, wpk1, W2, wpk2, cursor,
                                         binned);
    k_bucket<<<NBUK, 256, 0, stream>>>(binned, cursor, dinv, rowse, csr4);
    k_coef<<<NBUK, 256, 0, stream>>>(csr4, dinv, cursor);

    // ---- GEMMs + aggregations ----
    int gblocks = (N_NODES / 32 + 3) / 4;  // 782
    k_gemm1<<<gblocks, 256, 0, stream>>>(feat, loc, wpk1, h1h);
    k_agg1<<<(N_NODES + 3) / 4, 256, 0, stream>>>(h1h, dinv, rowse, csr4, loc,
                                                  b1, x1h);
    k_gemm2<<<gblocks, 256, 0, stream>>>(x1h, wpk2, h2h);
    k_out<<<(N_NODES + 3) / 4, 256, 0, stream>>>(h2h, dinv, rowse, csr4, b2,
                                                 out);
}

// Round 15
// 145.541 us; speedup vs baseline: 1.3573x; 1.0299x over previous
//
#include <hip/hip_runtime.h>
#include <hip/hip_fp16.h>

#define N_NODES 100000
#define N_EDGES 1250000
#define F_RAW 48
#define F_LOC 16
#define F1 48
#define F_OUT 64

#define NBUK 391             // ceil(N_NODES/256) dst buckets
#define PADB 4096            // per-bucket padded capacity (mean 3200, +16 sigma)
#define NB2 500              // edge chunks
#define CH2 (N_EDGES / NB2)  // 2500

#define GB1 ((N_NODES / 32 + 3) / 4)  // 782 gemm1 blocks
#define LROW 144                      // LDS x1 row stride (bank-spread, 16-mult)

typedef _Float16 half8_t __attribute__((ext_vector_type(8)));
typedef float floatx4 __attribute__((ext_vector_type(4)));

// ---------------------------------------------------------------------------
// W pack: Wpk[((ct*2+kt)*64+lane)*8+j] = W[kt*32+(lane>>4)*8+j][ct*16+(lane&15)]
// ---------------------------------------------------------------------------
__device__ void wprep_dev(const float* W, __half* Wpk, int M, int CT) {
    int lane = threadIdx.x;
    if (lane >= 64) return;
    for (int ct = 0; ct < CT; ++ct)
        for (int kt = 0; kt < 2; ++kt)
            for (int j = 0; j < 8; ++j) {
                int k = kt * 32 + (lane >> 4) * 8 + j;
                int c = ct * 16 + (lane & 15);
                Wpk[((ct * 2 + kt) * 64 + lane) * 8 + j] =
                    __float2half(W[k * M + c]);
            }
}

__device__ __forceinline__ void load_edge(const void* edges, int is32, int e,
                                          int& s, int& d) {
    if (is32) {
        const int* p = (const int*)edges;
        s = p[e];
        d = p[N_EDGES + e];
    } else {
        const long long* p = (const long long*)edges;
        s = (int)p[e];
        d = (int)p[N_EDGES + e];
    }
}

// ---------------------------------------------------------------------------
// prep2: blocks 0..499 = edge binning (per-block dtype detect, LDS hist,
// atomic block reservation, LDS-stashed scatter). Blocks 500/501 = W pack.
// binned entry = (dstlocal << 17) | src. cursor[k] counts entries in bucket k.
// ---------------------------------------------------------------------------
__global__ __launch_bounds__(512) void k_prep2(const void* edges,
                                               const float* W1, __half* wpk1,
                                               const float* W2, __half* wpk2,
                                               int* __restrict__ cursor,
                                               unsigned* __restrict__ binned) {
    int b = blockIdx.x, t = threadIdx.x;
    if (b >= NB2) {
        if (b == NB2)
            wprep_dev(W1, wpk1, F1, 3);
        else
            wprep_dev(W2, wpk2, F_OUT, 4);
        return;
    }
    __shared__ int hist[NBUK];
    __shared__ int2 stash[CH2];  // {bucket, entry} 20 KB
    __shared__ int s_any;
    if (t == 0) s_any = 0;
    for (int k = t; k < NBUK; k += 512) hist[k] = 0;
    __syncthreads();
    int e0 = b * CH2;
    // per-block dtype detect: int64 edges < 2^31 have all odd u32 words zero.
    const unsigned* eu = (const unsigned*)edges;
    if (eu[2 * (e0 + t) + 1] != 0u) atomicOr(&s_any, 1);
    __syncthreads();
    int is32 = s_any;
    for (int i = t; i < CH2; i += 512) {
        int s, d;
        load_edge(edges, is32, e0 + i, s, d);
        int bk = d >> 8;
        stash[i] = make_int2(bk, ((d & 255) << 17) | s);
        atomicAdd(&hist[bk], 1);
    }
    __syncthreads();
    for (int k = t; k < NBUK; k += 512) {
        int c = hist[k];
        hist[k] = (c ? atomicAdd(&cursor[k], c) : 0) + k * PADB;
    }
    __syncthreads();
    for (int i = t; i < CH2; i += 512) {
        int2 sd = stash[i];
        int p = atomicAdd(&hist[sd.x], 1);
        binned[p] = (unsigned)sd.y;
    }
}

// ---------------------------------------------------------------------------
// bucket: one block per bucket (256 nodes): dinv + rowse{start,end} +
// node-ordered csr4 within the bucket's padded region.
// ---------------------------------------------------------------------------
__global__ __launch_bounds__(256) void k_bucket(
    const unsigned* __restrict__ binned, const int* __restrict__ cursor,
    float* __restrict__ dinv, int2* __restrict__ rowse,
    unsigned* __restrict__ csr4) {
    int k = blockIdx.x, t = threadIdx.x;
    int lane = t & 63, wv = t >> 6;
    __shared__ int ldeg[256];
    __shared__ int wcnt[256];
    __shared__ int ws4[4];
    int base = k * PADB;
    int len = cursor[k];
    ldeg[t] = 0;
    __syncthreads();
    for (int i = t; i < len; i += 256)
        atomicAdd(&ldeg[binned[base + i] >> 17], 1);
    __syncthreads();
    int degv = ldeg[t];
    int x = degv;
#pragma unroll
    for (int off = 1; off < 64; off <<= 1) {
        int u = __shfl_up(x, off);
        if (lane >= off) x += u;
    }
    if (lane == 63) ws4[wv] = x;
    __syncthreads();
    int woff = 0;
    for (int w = 0; w < wv; ++w) woff += ws4[w];
    int excl = woff + x - degv;
    int node = k * 256 + t;
    if (node < N_NODES) {
        dinv[node] = rsqrtf((float)degv + 1.0f);
        rowse[node] = make_int2(base + excl, base + excl + degv);
    }
    wcnt[t] = base + excl;
    __syncthreads();
    for (int i = t; i < len; i += 256) {
        unsigned ent = binned[base + i];
        int p = atomicAdd(&wcnt[ent >> 17], 1);
        csr4[p] = ent & 0x1FFFFu;
    }
}

// ---------------------------------------------------------------------------
// cg1 (fused launch): blocks [0,NBUK) = coef stamp; [NBUK, NBUK+GB1) = gemm1.
// coef: csr4[i] = (src<<14) | fp16bits(dinv[src]).
// gemm1: h1 = concat(feat,loc)@W1, fp32 read direct, 128B rows, zero-pad 48..63
// ---------------------------------------------------------------------------
__global__ __launch_bounds__(256) void k_cg1(
    unsigned* __restrict__ csr4, const float* __restrict__ dinv,
    const int* __restrict__ cursor, const float* __restrict__ feat,
    const float* __restrict__ loc, const __half* __restrict__ Wpk,
    __half* __restrict__ Y) {
    if (blockIdx.x < NBUK) {
        int k = blockIdx.x;
        int end = k * PADB + cursor[k];
        for (int i = k * PADB + threadIdx.x; i < end; i += 256) {
            unsigned s = csr4[i];
            csr4[i] =
                (s << 14) | (unsigned)__half_as_ushort(__float2half(dinv[s]));
        }
        return;
    }
    int wid = threadIdx.x >> 6;
    int lane = threadIdx.x & 63;
    int nb = ((blockIdx.x - NBUK) * 4 + wid) * 32;
    if (nb >= N_NODES) return;
    half8_t b[3][2];
#pragma unroll
    for (int ct = 0; ct < 3; ++ct)
#pragma unroll
        for (int kt = 0; kt < 2; ++kt)
            b[ct][kt] = *reinterpret_cast<const half8_t*>(
                Wpk + ((ct * 2 + kt) * 64 + lane) * 8);
    int r = lane & 15;
    int slot = lane >> 4;
    half8_t a[2][2];
#pragma unroll
    for (int rt = 0; rt < 2; ++rt)
#pragma unroll
        for (int kt = 0; kt < 2; ++kt) {
            int sl = kt * 4 + slot;
            int node = nb + rt * 16 + r;
            const float* sp = (sl < 6)
                                  ? feat + (size_t)node * F_RAW + sl * 8
                                  : loc + (size_t)node * F_LOC + (sl - 6) * 8;
            float4 f0 = reinterpret_cast<const float4*>(sp)[0];
            float4 f1 = reinterpret_cast<const float4*>(sp)[1];
            half8_t h;
            h[0] = (_Float16)f0.x;
            h[1] = (_Float16)f0.y;
            h[2] = (_Float16)f0.z;
            h[3] = (_Float16)f0.w;
            h[4] = (_Float16)f1.x;
            h[5] = (_Float16)f1.y;
            h[6] = (_Float16)f1.z;
            h[7] = (_Float16)f1.w;
            a[rt][kt] = h;
        }
    floatx4 acc[2][3];
#pragma unroll
    for (int rt = 0; rt < 2; ++rt)
#pragma unroll
        for (int ct = 0; ct < 3; ++ct) {
            floatx4 z = {0.f, 0.f, 0.f, 0.f};
            z = __builtin_amdgcn_mfma_f32_16x16x32_f16(a[rt][0], b[ct][0], z, 0, 0, 0);
            z = __builtin_amdgcn_mfma_f32_16x16x32_f16(a[rt][1], b[ct][1], z, 0, 0, 0);
            acc[rt][ct] = z;
        }
    int row0 = (lane >> 4) * 4;
    int col = lane & 15;
#pragma unroll
    for (int rt = 0; rt < 2; ++rt)
#pragma unroll
        for (int ct = 0; ct < 3; ++ct)
#pragma unroll
            for (int j = 0; j < 4; ++j) {
                int node = nb + rt * 16 + row0 + j;
                Y[(size_t)node * 64 + ct * 16 + col] = __float2half(acc[rt][ct][j]);
            }
    int node = nb + (lane & 31);
    int slotp = 6 + (lane >> 5);
    *reinterpret_cast<int4*>(Y + (size_t)node * 64 + slotp * 8) =
        make_int4(0, 0, 0, 0);
}

// ---------------------------------------------------------------------------
// gather helpers: fp16 packed accumulate
// ---------------------------------------------------------------------------
__device__ __forceinline__ __half2 c2_from(unsigned A) {
    unsigned b = A & 0x3FFFu;
    unsigned p = b | (b << 16);
    return *reinterpret_cast<__half2*>(&p);
}

__device__ __forceinline__ void fma8h(const int4& p, __half2 c2, __half2 a[4]) {
    const __half2* h = reinterpret_cast<const __half2*>(&p);
#pragma unroll
    for (int j = 0; j < 4; ++j) a[j] = __hfma2(h[j], c2, a[j]);
}

__device__ __forceinline__ __half2 shfl_xor_h2(__half2 v, int m) {
    int i = *reinterpret_cast<int*>(&v);
    i = __shfl_xor(i, m);
    return *reinterpret_cast<__half2*>(&i);
}

// ---------------------------------------------------------------------------
// fused agg1 + gemm2: 512-thread block owns 32 nodes (8 waves x 4 nodes).
// Phase 1 (per wave, 4 sequential nodes): gather-agg h1, assemble x1 row
// [relu(agg*di + self*d2 + b1) (48) | loc (16)] -> LDS (rows of LROW bytes).
// Phase 2 (after barrier): wave w computes (rt,ct)=(w>>2,w&3) tile of the
// 32-node GEMM2 from LDS and writes h2.
// ---------------------------------------------------------------------------
__global__ __launch_bounds__(512) void k_aggemm(
    const __half* __restrict__ h1h, const float* __restrict__ dinv,
    const int2* __restrict__ rowse, const unsigned* __restrict__ csr4,
    const float* __restrict__ loc, const float* __restrict__ b1,
    const __half* __restrict__ Wpk2, __half* __restrict__ h2h) {
    __shared__ __align__(16) char lds_x1[32 * LROW];
    int t = threadIdx.x;
    int w = t >> 6;
    int lane = t & 63;
    int grp = lane >> 3;
    int l8 = lane & 7;
    int nb = blockIdx.x * 32;
    const char* h1l = reinterpret_cast<const char*>(h1h) + (l8 << 4);
#pragma unroll
    for (int it = 0; it < 4; ++it) {
        int nl = w * 4 + it;
        int node = nb + nl;  // N_NODES = 32*3125 exact, always valid
        int2 se = rowse[node];
        int r0 = se.x, r1 = se.y;
        float di = dinv[node];
        int4 hs = *reinterpret_cast<const int4*>(h1l + ((size_t)node << 7));
        int len = r1 - r0;
        int L = (len + 7) >> 3;
        int gs = r0 + grp * L;
        int ge = gs + L;
        if (ge > r1) ge = r1;
        __half2 z2 = __float2half2_rn(0.f);
        __half2 a0[4] = {z2, z2, z2, z2};
        __half2 a1[4] = {z2, z2, z2, z2};
        int e = gs;
        for (; e + 1 < ge; e += 2) {
            unsigned A = csr4[e];
            unsigned B = csr4[e + 1];
            int4 vA = *reinterpret_cast<const int4*>(h1l + ((A >> 14) << 7));
            int4 vB = *reinterpret_cast<const int4*>(h1l + ((B >> 14) << 7));
            fma8h(vA, c2_from(A), a0);
            fma8h(vB, c2_from(B), a1);
        }
        if (e < ge) {
            unsigned A = csr4[e];
            int4 vA = *reinterpret_cast<const int4*>(h1l + ((A >> 14) << 7));
            fma8h(vA, c2_from(A), a0);
        }
#pragma unroll
        for (int j = 0; j < 4; ++j) a0[j] = __hadd2(a0[j], a1[j]);
#pragma unroll
        for (int j = 0; j < 4; ++j) {
            a0[j] = __hadd2(a0[j], shfl_xor_h2(a0[j], 8));
            a0[j] = __hadd2(a0[j], shfl_xor_h2(a0[j], 16));
            a0[j] = __hadd2(a0[j], shfl_xor_h2(a0[j], 32));
        }
        if (lane < 8) {
            __half2 q[4];
            if (l8 < 6) {
                float d2 = di * di;
                const float4* b1v = reinterpret_cast<const float4*>(b1);
                float4 bA = b1v[l8 * 2];
                float4 bB = b1v[l8 * 2 + 1];
                float bb[8] = {bA.x, bA.y, bA.z, bA.w, bB.x, bB.y, bB.z, bB.w};
                const __half2* hh = reinterpret_cast<const __half2*>(&hs);
#pragma unroll
                for (int j = 0; j < 4; ++j) {
                    float2 tt = __half22float2(hh[j]);
                    float2 ag = __half22float2(a0[j]);
                    float o0 =
                        fmaxf(fmaf(ag.x, di, fmaf(tt.x, d2, bb[2 * j])), 0.f);
                    float o1 = fmaxf(
                        fmaf(ag.y, di, fmaf(tt.y, d2, bb[2 * j + 1])), 0.f);
                    q[j] = __halves2half2(__float2half(o0), __float2half(o1));
                }
            } else {
                const float* lp = loc + (size_t)node * F_LOC + (l8 - 6) * 8;
                float4 f0 = reinterpret_cast<const float4*>(lp)[0];
                float4 f1 = reinterpret_cast<const float4*>(lp)[1];
                q[0] = __halves2half2(__float2half(f0.x), __float2half(f0.y));
                q[1] = __halves2half2(__float2half(f0.z), __float2half(f0.w));
                q[2] = __halves2half2(__float2half(f1.x), __float2half(f1.y));
                q[3] = __halves2half2(__float2half(f1.z), __float2half(f1.w));
            }
            *reinterpret_cast<int4*>(&lds_x1[nl * LROW + l8 * 16]) =
                *reinterpret_cast<int4*>(q);
        }
    }
    __syncthreads();
    // ---- GEMM2 tile: wave w -> rt = w>>2, ct = w&3 ----
    int rt = w >> 2;
    int ct = w & 3;
    half8_t bfr[2];
#pragma unroll
    for (int kt = 0; kt < 2; ++kt)
        bfr[kt] = *reinterpret_cast<const half8_t*>(
            Wpk2 + ((ct * 2 + kt) * 64 + lane) * 8);
    int r = lane & 15;
    int ks = (lane >> 4) * 8;
    half8_t afr[2];
#pragma unroll
    for (int kt = 0; kt < 2; ++kt)
        afr[kt] = *reinterpret_cast<const half8_t*>(
            &lds_x1[(rt * 16 + r) * LROW + kt * 64 + ks * 2]);
    floatx4 z = {0.f, 0.f, 0.f, 0.f};
    z = __builtin_amdgcn_mfma_f32_16x16x32_f16(afr[0], bfr[0], z, 0, 0, 0);
    z = __builtin_amdgcn_mfma_f32_16x16x32_f16(afr[1], bfr[1], z, 0, 0, 0);
    int row0 = (lane >> 4) * 4;
    int col = lane & 15;
#pragma unroll
    for (int j = 0; j < 4; ++j) {
        int node = nb + rt * 16 + row0 + j;
        h2h[(size_t)node * 64 + ct * 16 + col] = __float2half(z[j]);
    }
}

// ---------------------------------------------------------------------------
// agg2 + self + bias -> out (fp32)
// ---------------------------------------------------------------------------
__global__ __launch_bounds__(256) void k_out(
    const __half* __restrict__ h2h, const float* __restrict__ dinv,
    const int2* __restrict__ rowse, const unsigned* __restrict__ csr4,
    const float* __restrict__ b2, float* __restrict__ out) {
    int wave = threadIdx.x >> 6;
    int lane = threadIdx.x & 63;
    int grp = lane >> 3;
    int l8 = lane & 7;
    int node = blockIdx.x * 4 + wave;
    if (node >= N_NODES) return;
    int2 se = rowse[node];
    int r0 = se.x, r1 = se.y;
    const char* h2l = reinterpret_cast<const char*>(h2h) + (l8 << 4);
    float di = dinv[node];
    int4 hs = *reinterpret_cast<const int4*>(h2l + ((size_t)node << 7));
    int len = r1 - r0;
    int L = (len + 7) >> 3;
    int gs = r0 + grp * L;
    int ge = gs + L;
    if (ge > r1) ge = r1;
    __half2 z2 = __float2half2_rn(0.f);
    __half2 a0[4] = {z2, z2, z2, z2};
    __half2 a1[4] = {z2, z2, z2, z2};
    int e = gs;
    for (; e + 1 < ge; e += 2) {
        unsigned A = csr4[e];
        unsigned B = csr4[e + 1];
        int4 vA = *reinterpret_cast<const int4*>(h2l + ((A >> 14) << 7));
        int4 vB = *reinterpret_cast<const int4*>(h2l + ((B >> 14) << 7));
        fma8h(vA, c2_from(A), a0);
        fma8h(vB, c2_from(B), a1);
    }
    if (e < ge) {
        unsigned A = csr4[e];
        int4 vA = *reinterpret_cast<const int4*>(h2l + ((A >> 14) << 7));
        fma8h(vA, c2_from(A), a0);
    }
#pragma unroll
    for (int j = 0; j < 4; ++j) a0[j] = __hadd2(a0[j], a1[j]);
#pragma unroll
    for (int j = 0; j < 4; ++j) {
        a0[j] = __hadd2(a0[j], shfl_xor_h2(a0[j], 8));
        a0[j] = __hadd2(a0[j], shfl_xor_h2(a0[j], 16));
        a0[j] = __hadd2(a0[j], shfl_xor_h2(a0[j], 32));
    }
    if (lane < 8) {
        float d2 = di * di;
        const float4* b2v = reinterpret_cast<const float4*>(b2);
        float4 bA = b2v[l8 * 2];
        float4 bB = b2v[l8 * 2 + 1];
        float bb[8] = {bA.x, bA.y, bA.z, bA.w, bB.x, bB.y, bB.z, bB.w};
        const __half2* hh = reinterpret_cast<const __half2*>(&hs);
        float o[8];
#pragma unroll
        for (int j = 0; j < 4; ++j) {
            float2 t = __half22float2(hh[j]);
            float2 ag = __half22float2(a0[j]);
            o[2 * j] = fmaf(ag.x, di, fmaf(t.x, d2, bb[2 * j]));
            o[2 * j + 1] = fmaf(ag.y, di, fmaf(t.y, d2, bb[2 * j + 1]));
        }
        float4* ov = reinterpret_cast<float4*>(out + (size_t)node * F_OUT);
        ov[l8 * 2] = make_float4(o[0], o[1], o[2], o[3]);
        ov[l8 * 2 + 1] = make_float4(o[4], o[5], o[6], o[7]);
    }
}

extern "C" void kernel_launch(void* const* d_in, const int* in_sizes, int n_in,
                              void* d_out, int out_size, void* d_ws,
                              size_t ws_size, hipStream_t stream) {
    const void* edges = d_in[0];
    const float* feat = (const float*)d_in[1];
    const float* loc = (const float*)d_in[2];
    const float* W1 = (const float*)d_in[3];
    const float* b1 = (const float*)d_in[4];
    const float* W2 = (const float*)d_in[5];
    const float* b2 = (const float*)d_in[6];
    float* out = (float*)d_out;

    // All offsets multiples of 128 (128B feature rows must be line-aligned:
    // r13's 32-mod-128 base cost +50% gather fetch).
    char* ws = (char*)d_ws;
    float* dinv = (float*)(ws + 0);                //    400,000
    int2* rowse = (int2*)(ws + 400000);            //    800,000
    int* cursor = (int*)(ws + 1200000);            //      1,664 (pad)
    unsigned* binned = (unsigned*)(ws + 1201664);  //  6,406,144
    unsigned* csr4 = (unsigned*)(ws + 7607808);    //  6,406,144
    __half* h1h = (__half*)(ws + 14013952);        // 12,800,000
    __half* h2h = (__half*)(ws + 26813952);        // 12,800,000
    __half* wpk1 = (__half*)(ws + 39613952);       //      6,144
    __half* wpk2 = (__half*)(ws + 39620096);       //      8,192

    hipMemsetAsync(cursor, 0, NBUK * 4, stream);

    // ---- CSR build: single-pass binning + W pack (fused grid) ----
    k_prep2<<<NB2 + 2, 512, 0, stream>>>(edges, W1, wpk1, W2, wpk2, cursor,
                                         binned);
    k_bucket<<<NBUK, 256, 0, stream>>>(binned, cursor, dinv, rowse, csr4);

    // ---- coef + gemm1 (fused grid) ----
    k_cg1<<<NBUK + GB1, 256, 0, stream>>>(csr4, dinv, cursor, feat, loc, wpk1,
                                          h1h);

    // ---- fused agg1 + gemm2 ----
    k_aggemm<<<N_NODES / 32, 512, 0, stream>>>(h1h, dinv, rowse, csr4, loc,
                                               b1, wpk2, h2h);

    // ---- agg2 -> out ----
    k_out<<<(N_NODES + 3) / 4, 256, 0, stream>>>(h2h, dinv, rowse, csr4, b2,
                                                 out);
}

// Round 16
// 140.989 us; speedup vs baseline: 1.4012x; 1.0323x over previous
//
#include <hip/hip_runtime.h>
#include <hip/hip_fp16.h>

#define N_NODES 100000
#define N_EDGES 1250000
#define F_RAW 48
#define F_LOC 16
#define F1 48
#define F_OUT 64

#define NBUK 391             // ceil(N_NODES/256) dst buckets
#define PADB 4096            // per-bucket padded capacity (mean 3200, +16 sigma)
#define NB2 500              // edge chunks
#define CH2 (N_EDGES / NB2)  // 2500

#define GB1 ((N_NODES / 32 + 3) / 4)  // 782 gemm1 blocks
#define LROW 144                      // LDS x1 row stride

typedef _Float16 half8_t __attribute__((ext_vector_type(8)));
typedef float floatx4 __attribute__((ext_vector_type(4)));

// ---------------------------------------------------------------------------
// W pack: Wpk[((ct*2+kt)*64+lane)*8+j] = W[kt*32+(lane>>4)*8+j][ct*16+(lane&15)]
// ---------------------------------------------------------------------------
__device__ void wprep_dev(const float* W, __half* Wpk, int M, int CT) {
    int lane = threadIdx.x;
    if (lane >= 64) return;
    for (int ct = 0; ct < CT; ++ct)
        for (int kt = 0; kt < 2; ++kt)
            for (int j = 0; j < 8; ++j) {
                int k = kt * 32 + (lane >> 4) * 8 + j;
                int c = ct * 16 + (lane & 15);
                Wpk[((ct * 2 + kt) * 64 + lane) * 8 + j] =
                    __float2half(W[k * M + c]);
            }
}

__device__ __forceinline__ void load_edge(const void* edges, int is32, int e,
                                          int& s, int& d) {
    if (is32) {
        const int* p = (const int*)edges;
        s = p[e];
        d = p[N_EDGES + e];
    } else {
        const long long* p = (const long long*)edges;
        s = (int)p[e];
        d = (int)p[N_EDGES + e];
    }
}

// ---------------------------------------------------------------------------
// prep2: blocks 0..499 = edge binning (per-block dtype detect, LDS hist,
// atomic block reservation, LDS-stashed scatter). Blocks 500/501 = W pack.
// binned entry = (dstlocal << 17) | src. cursor[k] counts entries in bucket k.
// ---------------------------------------------------------------------------
__global__ __launch_bounds__(512) void k_prep2(const void* edges,
                                               const float* W1, __half* wpk1,
                                               const float* W2, __half* wpk2,
                                               int* __restrict__ cursor,
                                               unsigned* __restrict__ binned) {
    int b = blockIdx.x, t = threadIdx.x;
    if (b >= NB2) {
        if (b == NB2)
            wprep_dev(W1, wpk1, F1, 3);
        else
            wprep_dev(W2, wpk2, F_OUT, 4);
        return;
    }
    __shared__ int hist[NBUK];
    __shared__ int2 stash[CH2];  // {bucket, entry} 20 KB
    __shared__ int s_any;
    if (t == 0) s_any = 0;
    for (int k = t; k < NBUK; k += 512) hist[k] = 0;
    __syncthreads();
    int e0 = b * CH2;
    // per-block dtype detect: int64 edges < 2^31 have all odd u32 words zero.
    const unsigned* eu = (const unsigned*)edges;
    if (eu[2 * (e0 + t) + 1] != 0u) atomicOr(&s_any, 1);
    __syncthreads();
    int is32 = s_any;
    for (int i = t; i < CH2; i += 512) {
        int s, d;
        load_edge(edges, is32, e0 + i, s, d);
        int bk = d >> 8;
        stash[i] = make_int2(bk, ((d & 255) << 17) | s);
        atomicAdd(&hist[bk], 1);
    }
    __syncthreads();
    for (int k = t; k < NBUK; k += 512) {
        int c = hist[k];
        hist[k] = (c ? atomicAdd(&cursor[k], c) : 0) + k * PADB;
    }
    __syncthreads();
    for (int i = t; i < CH2; i += 512) {
        int2 sd = stash[i];
        int p = atomicAdd(&hist[sd.x], 1);
        binned[p] = (unsigned)sd.y;
    }
}

// ---------------------------------------------------------------------------
// bucket+gemm1 (fused grid):
// blocks [0,NBUK): per-bucket dinv + rowse{start,end} + node-ordered csr4.
// blocks [NBUK,NBUK+GB1): gemm1 h1 = concat(feat,loc)@W1 (fp32 read direct,
// 128B rows, zero-pad cols 48..63). Independent work, same launch.
// ---------------------------------------------------------------------------
__global__ __launch_bounds__(256) void k_bg1(
    const unsigned* __restrict__ binned, const int* __restrict__ cursor,
    float* __restrict__ dinv, int2* __restrict__ rowse,
    unsigned* __restrict__ csr4, const float* __restrict__ feat,
    const float* __restrict__ loc, const __half* __restrict__ Wpk,
    __half* __restrict__ Y) {
    if (blockIdx.x < NBUK) {
        int k = blockIdx.x, t = threadIdx.x;
        int lane = t & 63, wv = t >> 6;
        __shared__ int ldeg[256];
        __shared__ int wcnt[256];
        __shared__ int ws4[4];
        int base = k * PADB;
        int len = cursor[k];
        ldeg[t] = 0;
        __syncthreads();
        for (int i = t; i < len; i += 256)
            atomicAdd(&ldeg[binned[base + i] >> 17], 1);
        __syncthreads();
        int degv = ldeg[t];
        int x = degv;
#pragma unroll
        for (int off = 1; off < 64; off <<= 1) {
            int u = __shfl_up(x, off);
            if (lane >= off) x += u;
        }
        if (lane == 63) ws4[wv] = x;
        __syncthreads();
        int woff = 0;
        for (int w = 0; w < wv; ++w) woff += ws4[w];
        int excl = woff + x - degv;
        int node = k * 256 + t;
        if (node < N_NODES) {
            dinv[node] = rsqrtf((float)degv + 1.0f);
            rowse[node] = make_int2(base + excl, base + excl + degv);
        }
        wcnt[t] = base + excl;
        __syncthreads();
        for (int i = t; i < len; i += 256) {
            unsigned ent = binned[base + i];
            int p = atomicAdd(&wcnt[ent >> 17], 1);
            csr4[p] = ent & 0x1FFFFu;
        }
        return;
    }
    // ---- gemm1 ----
    int wid = threadIdx.x >> 6;
    int lane = threadIdx.x & 63;
    int nb = ((blockIdx.x - NBUK) * 4 + wid) * 32;
    if (nb >= N_NODES) return;
    half8_t b[3][2];
#pragma unroll
    for (int ct = 0; ct < 3; ++ct)
#pragma unroll
        for (int kt = 0; kt < 2; ++kt)
            b[ct][kt] = *reinterpret_cast<const half8_t*>(
                Wpk + ((ct * 2 + kt) * 64 + lane) * 8);
    int r = lane & 15;
    int slot = lane >> 4;
    half8_t a[2][2];
#pragma unroll
    for (int rt = 0; rt < 2; ++rt)
#pragma unroll
        for (int kt = 0; kt < 2; ++kt) {
            int sl = kt * 4 + slot;
            int node = nb + rt * 16 + r;
            const float* sp = (sl < 6)
                                  ? feat + (size_t)node * F_RAW + sl * 8
                                  : loc + (size_t)node * F_LOC + (sl - 6) * 8;
            float4 f0 = reinterpret_cast<const float4*>(sp)[0];
            float4 f1 = reinterpret_cast<const float4*>(sp)[1];
            half8_t h;
            h[0] = (_Float16)f0.x;
            h[1] = (_Float16)f0.y;
            h[2] = (_Float16)f0.z;
            h[3] = (_Float16)f0.w;
            h[4] = (_Float16)f1.x;
            h[5] = (_Float16)f1.y;
            h[6] = (_Float16)f1.z;
            h[7] = (_Float16)f1.w;
            a[rt][kt] = h;
        }
    floatx4 acc[2][3];
#pragma unroll
    for (int rt = 0; rt < 2; ++rt)
#pragma unroll
        for (int ct = 0; ct < 3; ++ct) {
            floatx4 z = {0.f, 0.f, 0.f, 0.f};
            z = __builtin_amdgcn_mfma_f32_16x16x32_f16(a[rt][0], b[ct][0], z, 0, 0, 0);
            z = __builtin_amdgcn_mfma_f32_16x16x32_f16(a[rt][1], b[ct][1], z, 0, 0, 0);
            acc[rt][ct] = z;
        }
    int row0 = (lane >> 4) * 4;
    int col = lane & 15;
#pragma unroll
    for (int rt = 0; rt < 2; ++rt)
#pragma unroll
        for (int ct = 0; ct < 3; ++ct)
#pragma unroll
            for (int j = 0; j < 4; ++j) {
                int node = nb + rt * 16 + row0 + j;
                Y[(size_t)node * 64 + ct * 16 + col] = __float2half(acc[rt][ct][j]);
            }
    int node = nb + (lane & 31);
    int slotp = 6 + (lane >> 5);
    *reinterpret_cast<int4*>(Y + (size_t)node * 64 + slotp * 8) =
        make_int4(0, 0, 0, 0);
}

// ---------------------------------------------------------------------------
// coef: per bucket, stamp csr4[i] = (src<<14) | fp16bits(dinv[src]).
// ---------------------------------------------------------------------------
__global__ __launch_bounds__(256) void k_coef(unsigned* __restrict__ csr4,
                                              const float* __restrict__ dinv,
                                              const int* __restrict__ cursor) {
    int k = blockIdx.x;
    int end = k * PADB + cursor[k];
    for (int i = k * PADB + threadIdx.x; i < end; i += 256) {
        unsigned s = csr4[i];
        csr4[i] = (s << 14) | (unsigned)__half_as_ushort(__float2half(dinv[s]));
    }
}

// ---------------------------------------------------------------------------
// gather helpers: fp16 packed accumulate
// ---------------------------------------------------------------------------
__device__ __forceinline__ __half2 c2_from(unsigned A) {
    unsigned b = A & 0x3FFFu;
    unsigned p = b | (b << 16);
    return *reinterpret_cast<__half2*>(&p);
}

__device__ __forceinline__ void fma8h(const int4& p, __half2 c2, __half2 a[4]) {
    const __half2* h = reinterpret_cast<const __half2*>(&p);
#pragma unroll
    for (int j = 0; j < 4; ++j) a[j] = __hfma2(h[j], c2, a[j]);
}

__device__ __forceinline__ __half2 shfl_xor_h2(__half2 v, int m) {
    int i = *reinterpret_cast<int*>(&v);
    i = __shfl_xor(i, m);
    return *reinterpret_cast<__half2*>(&i);
}

// ---------------------------------------------------------------------------
// fused agg1 + gemm2: 512-thread block owns 32 nodes (8 waves x 4 nodes).
// Phase 1: gather-agg h1 -> x1 row [relu(...)|loc] -> LDS.
// Phase 2: wave w computes (rt,ct)=(w>>2,w&3) tile of GEMM2, writes h2.
// ---------------------------------------------------------------------------
__global__ __launch_bounds__(512) void k_aggemm(
    const __half* __restrict__ h1h, const float* __restrict__ dinv,
    const int2* __restrict__ rowse, const unsigned* __restrict__ csr4,
    const float* __restrict__ loc, const float* __restrict__ b1,
    const __half* __restrict__ Wpk2, __half* __restrict__ h2h) {
    __shared__ __align__(16) char lds_x1[32 * LROW];
    int t = threadIdx.x;
    int w = t >> 6;
    int lane = t & 63;
    int grp = lane >> 3;
    int l8 = lane & 7;
    int nb = blockIdx.x * 32;
    const char* h1l = reinterpret_cast<const char*>(h1h) + (l8 << 4);
#pragma unroll
    for (int it = 0; it < 4; ++it) {
        int nl = w * 4 + it;
        int node = nb + nl;
        int2 se = rowse[node];
        int r0 = se.x, r1 = se.y;
        float di = dinv[node];
        int4 hs = *reinterpret_cast<const int4*>(h1l + ((size_t)node << 7));
        int len = r1 - r0;
        int L = (len + 7) >> 3;
        int gs = r0 + grp * L;
        int ge = gs + L;
        if (ge > r1) ge = r1;
        __half2 z2 = __float2half2_rn(0.f);
        __half2 a0[4] = {z2, z2, z2, z2};
        __half2 a1[4] = {z2, z2, z2, z2};
        int e = gs;
        for (; e + 1 < ge; e += 2) {
            unsigned A = csr4[e];
            unsigned B = csr4[e + 1];
            int4 vA = *reinterpret_cast<const int4*>(h1l + ((A >> 14) << 7));
            int4 vB = *reinterpret_cast<const int4*>(h1l + ((B >> 14) << 7));
            fma8h(vA, c2_from(A), a0);
            fma8h(vB, c2_from(B), a1);
        }
        if (e < ge) {
            unsigned A = csr4[e];
            int4 vA = *reinterpret_cast<const int4*>(h1l + ((A >> 14) << 7));
            fma8h(vA, c2_from(A), a0);
        }
#pragma unroll
        for (int j = 0; j < 4; ++j) a0[j] = __hadd2(a0[j], a1[j]);
#pragma unroll
        for (int j = 0; j < 4; ++j) {
            a0[j] = __hadd2(a0[j], shfl_xor_h2(a0[j], 8));
            a0[j] = __hadd2(a0[j], shfl_xor_h2(a0[j], 16));
            a0[j] = __hadd2(a0[j], shfl_xor_h2(a0[j], 32));
        }
        if (lane < 8) {
            __half2 q[4];
            if (l8 < 6) {
                float d2 = di * di;
                const float4* b1v = reinterpret_cast<const float4*>(b1);
                float4 bA = b1v[l8 * 2];
                float4 bB = b1v[l8 * 2 + 1];
                float bb[8] = {bA.x, bA.y, bA.z, bA.w, bB.x, bB.y, bB.z, bB.w};
                const __half2* hh = reinterpret_cast<const __half2*>(&hs);
#pragma unroll
                for (int j = 0; j < 4; ++j) {
                    float2 tt = __half22float2(hh[j]);
                    float2 ag = __half22float2(a0[j]);
                    float o0 =
                        fmaxf(fmaf(ag.x, di, fmaf(tt.x, d2, bb[2 * j])), 0.f);
                    float o1 = fmaxf(
                        fmaf(ag.y, di, fmaf(tt.y, d2, bb[2 * j + 1])), 0.f);
                    q[j] = __halves2half2(__float2half(o0), __float2half(o1));
                }
            } else {
                const float* lp = loc + (size_t)node * F_LOC + (l8 - 6) * 8;
                float4 f0 = reinterpret_cast<const float4*>(lp)[0];
                float4 f1 = reinterpret_cast<const float4*>(lp)[1];
                q[0] = __halves2half2(__float2half(f0.x), __float2half(f0.y));
                q[1] = __halves2half2(__float2half(f0.z), __float2half(f0.w));
                q[2] = __halves2half2(__float2half(f1.x), __float2half(f1.y));
                q[3] = __halves2half2(__float2half(f1.z), __float2half(f1.w));
            }
            *reinterpret_cast<int4*>(&lds_x1[nl * LROW + l8 * 16]) =
                *reinterpret_cast<int4*>(q);
        }
    }
    __syncthreads();
    int rt = w >> 2;
    int ct = w & 3;
    half8_t bfr[2];
#pragma unroll
    for (int kt = 0; kt < 2; ++kt)
        bfr[kt] = *reinterpret_cast<const half8_t*>(
            Wpk2 + ((ct * 2 + kt) * 64 + lane) * 8);
    int r = lane & 15;
    int ks = (lane >> 4) * 8;
    half8_t afr[2];
#pragma unroll
    for (int kt = 0; kt < 2; ++kt)
        afr[kt] = *reinterpret_cast<const half8_t*>(
            &lds_x1[(rt * 16 + r) * LROW + kt * 64 + ks * 2]);
    floatx4 z = {0.f, 0.f, 0.f, 0.f};
    z = __builtin_amdgcn_mfma_f32_16x16x32_f16(afr[0], bfr[0], z, 0, 0, 0);
    z = __builtin_amdgcn_mfma_f32_16x16x32_f16(afr[1], bfr[1], z, 0, 0, 0);
    int row0 = (lane >> 4) * 4;
    int col = lane & 15;
#pragma unroll
    for (int j = 0; j < 4; ++j) {
        int node = nb + rt * 16 + row0 + j;
        h2h[(size_t)node * 64 + ct * 16 + col] = __float2half(z[j]);
    }
}

// ---------------------------------------------------------------------------
// agg2 + self + bias -> out (fp32)
// ---------------------------------------------------------------------------
__global__ __launch_bounds__(256) void k_out(
    const __half* __restrict__ h2h, const float* __restrict__ dinv,
    const int2* __restrict__ rowse, const unsigned* __restrict__ csr4,
    const float* __restrict__ b2, float* __restrict__ out) {
    int wave = threadIdx.x >> 6;
    int lane = threadIdx.x & 63;
    int grp = lane >> 3;
    int l8 = lane & 7;
    int node = blockIdx.x * 4 + wave;
    if (node >= N_NODES) return;
    int2 se = rowse[node];
    int r0 = se.x, r1 = se.y;
    const char* h2l = reinterpret_cast<const char*>(h2h) + (l8 << 4);
    float di = dinv[node];
    int4 hs = *reinterpret_cast<const int4*>(h2l + ((size_t)node << 7));
    int len = r1 - r0;
    int L = (len + 7) >> 3;
    int gs = r0 + grp * L;
    int ge = gs + L;
    if (ge > r1) ge = r1;
    __half2 z2 = __float2half2_rn(0.f);
    __half2 a0[4] = {z2, z2, z2, z2};
    __half2 a1[4] = {z2, z2, z2, z2};
    int e = gs;
    for (; e + 1 < ge; e += 2) {
        unsigned A = csr4[e];
        unsigned B = csr4[e + 1];
        int4 vA = *reinterpret_cast<const int4*>(h2l + ((A >> 14) << 7));
        int4 vB = *reinterpret_cast<const int4*>(h2l + ((B >> 14) << 7));
        fma8h(vA, c2_from(A), a0);
        fma8h(vB, c2_from(B), a1);
    }
    if (e < ge) {
        unsigned A = csr4[e];
        int4 vA = *reinterpret_cast<const int4*>(h2l + ((A >> 14) << 7));
        fma8h(vA, c2_from(A), a0);
    }
#pragma unroll
    for (int j = 0; j < 4; ++j) a0[j] = __hadd2(a0[j], a1[j]);
#pragma unroll
    for (int j = 0; j < 4; ++j) {
        a0[j] = __hadd2(a0[j], shfl_xor_h2(a0[j], 8));
        a0[j] = __hadd2(a0[j], shfl_xor_h2(a0[j], 16));
        a0[j] = __hadd2(a0[j], shfl_xor_h2(a0[j], 32));
    }
    if (lane < 8) {
        float d2 = di * di;
        const float4* b2v = reinterpret_cast<const float4*>(b2);
        float4 bA = b2v[l8 * 2];
        float4 bB = b2v[l8 * 2 + 1];
        float bb[8] = {bA.x, bA.y, bA.z, bA.w, bB.x, bB.y, bB.z, bB.w};
        const __half2* hh = reinterpret_cast<const __half2*>(&hs);
        float o[8];
#pragma unroll
        for (int j = 0; j < 4; ++j) {
            float2 t = __half22float2(hh[j]);
            float2 ag = __half22float2(a0[j]);
            o[2 * j] = fmaf(ag.x, di, fmaf(t.x, d2, bb[2 * j]));
            o[2 * j + 1] = fmaf(ag.y, di, fmaf(t.y, d2, bb[2 * j + 1]));
        }
        float4* ov = reinterpret_cast<float4*>(out + (size_t)node * F_OUT);
        ov[l8 * 2] = make_float4(o[0], o[1], o[2], o[3]);
        ov[l8 * 2 + 1] = make_float4(o[4], o[5], o[6], o[7]);
    }
}

extern "C" void kernel_launch(void* const* d_in, const int* in_sizes, int n_in,
                              void* d_out, int out_size, void* d_ws,
                              size_t ws_size, hipStream_t stream) {
    const void* edges = d_in[0];
    const float* feat = (const float*)d_in[1];
    const float* loc = (const float*)d_in[2];
    const float* W1 = (const float*)d_in[3];
    const float* b1 = (const float*)d_in[4];
    const float* W2 = (const float*)d_in[5];
    const float* b2 = (const float*)d_in[6];
    float* out = (float*)d_out;

    // All offsets multiples of 128 (128B feature rows must be line-aligned:
    // r13's 32-mod-128 base cost +50% gather fetch).
    char* ws = (char*)d_ws;
    float* dinv = (float*)(ws + 0);                //    400,000
    int2* rowse = (int2*)(ws + 400000);            //    800,000
    int* cursor = (int*)(ws + 1200000);            //      1,664 (pad)
    unsigned* binned = (unsigned*)(ws + 1201664);  //  6,406,144
    unsigned* csr4 = (unsigned*)(ws + 7607808);    //  6,406,144
    __half* h1h = (__half*)(ws + 14013952);        // 12,800,000
    __half* h2h = (__half*)(ws + 26813952);        // 12,800,000
    __half* wpk1 = (__half*)(ws + 39613952);       //      6,144
    __half* wpk2 = (__half*)(ws + 39620096);       //      8,192

    hipMemsetAsync(cursor, 0, NBUK * 4, stream);

    // ---- CSR binning + W pack (fused grid) ----
    k_prep2<<<NB2 + 2, 512, 0, stream>>>(edges, W1, wpk1, W2, wpk2, cursor,
                                         binned);
    // ---- bucket build + gemm1 (fused grid; independent halves) ----
    k_bg1<<<NBUK + GB1, 256, 0, stream>>>(binned, cursor, dinv, rowse, csr4,
                                          feat, loc, wpk1, h1h);
    // ---- coef stamp ----
    k_coef<<<NBUK, 256, 0, stream>>>(csr4, dinv, cursor);
    // ---- fused agg1 + gemm2 ----
    k_aggemm<<<N_NODES / 32, 512, 0, stream>>>(h1h, dinv, rowse, csr4, loc,
                                               b1, wpk2, h2h);
    // ---- agg2 -> out ----
    k_out<<<(N_NODES + 3) / 4, 256, 0, stream>>>(h2h, dinv, rowse, csr4, b2,
                                                 out);
}

// Round 17
// 135.913 us; speedup vs baseline: 1.4535x; 1.0373x over previous
//
#include <hip/hip_runtime.h>
#include <hip/hip_fp16.h>

#define N_NODES 100000
#define N_EDGES 1250000
#define F_RAW 48
#define F_LOC 16
#define F1 48
#define F_OUT 64

#define NBUK 391             // ceil(N_NODES/256) dst buckets
#define PADB 4096            // per-bucket padded capacity (mean 3200, +16 sigma)
#define NB2 250              // edge chunks
#define CH2 (N_EDGES / NB2)  // 5000

#define GB1 ((N_NODES / 32 + 3) / 4)  // 782 gemm1 blocks
#define LROW 144                      // LDS x1 row stride

typedef _Float16 half8_t __attribute__((ext_vector_type(8)));
typedef float floatx4 __attribute__((ext_vector_type(4)));

// ---------------------------------------------------------------------------
// W pack: Wpk[((ct*2+kt)*64+lane)*8+j] = W[kt*32+(lane>>4)*8+j][ct*16+(lane&15)]
// ---------------------------------------------------------------------------
__device__ void wprep_dev(const float* W, __half* Wpk, int M, int CT) {
    int lane = threadIdx.x;
    if (lane >= 64) return;
    for (int ct = 0; ct < CT; ++ct)
        for (int kt = 0; kt < 2; ++kt)
            for (int j = 0; j < 8; ++j) {
                int k = kt * 32 + (lane >> 4) * 8 + j;
                int c = ct * 16 + (lane & 15);
                Wpk[((ct * 2 + kt) * 64 + lane) * 8 + j] =
                    __float2half(W[k * M + c]);
            }
}

__device__ __forceinline__ void load_edge(const void* edges, int is32, int e,
                                          int& s, int& d) {
    if (is32) {
        const int* p = (const int*)edges;
        s = p[e];
        d = p[N_EDGES + e];
    } else {
        const long long* p = (const long long*)edges;
        s = (int)p[e];
        d = (int)p[N_EDGES + e];
    }
}

// ---------------------------------------------------------------------------
// prep2: blocks 0..NB2-1 = edge binning (per-block dtype detect, LDS hist,
// atomic block reservation, LDS-stashed scatter). Blocks NB2/NB2+1 = W pack.
// binned entry = (dstlocal << 17) | src. cursor[k] counts entries in bucket k.
// CH2=5000: avg (block,bucket) run = 12.8 entries = 51B, ~one line per run.
// ---------------------------------------------------------------------------
__global__ __launch_bounds__(512) void k_prep2(const void* edges,
                                               const float* W1, __half* wpk1,
                                               const float* W2, __half* wpk2,
                                               int* __restrict__ cursor,
                                               unsigned* __restrict__ binned) {
    int b = blockIdx.x, t = threadIdx.x;
    if (b >= NB2) {
        if (b == NB2)
            wprep_dev(W1, wpk1, F1, 3);
        else
            wprep_dev(W2, wpk2, F_OUT, 4);
        return;
    }
    __shared__ int hist[NBUK];
    __shared__ int2 stash[CH2];  // {bucket, entry} 40 KB
    __shared__ int s_any;
    if (t == 0) s_any = 0;
    for (int k = t; k < NBUK; k += 512) hist[k] = 0;
    __syncthreads();
    int e0 = b * CH2;
    // per-block dtype detect: int64 edges < 2^31 have all odd u32 words zero.
    const unsigned* eu = (const unsigned*)edges;
    if (eu[2 * (e0 + t) + 1] != 0u) atomicOr(&s_any, 1);
    __syncthreads();
    int is32 = s_any;
    for (int i = t; i < CH2; i += 512) {
        int s, d;
        load_edge(edges, is32, e0 + i, s, d);
        int bk = d >> 8;
        stash[i] = make_int2(bk, ((d & 255) << 17) | s);
        atomicAdd(&hist[bk], 1);
    }
    __syncthreads();
    for (int k = t; k < NBUK; k += 512) {
        int c = hist[k];
        hist[k] = (c ? atomicAdd(&cursor[k], c) : 0) + k * PADB;
    }
    __syncthreads();
    for (int i = t; i < CH2; i += 512) {
        int2 sd = stash[i];
        int p = atomicAdd(&hist[sd.x], 1);
        binned[p] = (unsigned)sd.y;
    }
}

// ---------------------------------------------------------------------------
// bucket+gemm1 (fused grid):
// blocks [0,NBUK): per-bucket dinv + rowse{start,end} + node-ordered csr4.
// blocks [NBUK,NBUK+GB1): gemm1 h1 = concat(feat,loc)@W1 (fp32 read direct,
// 128B rows, zero-pad cols 48..63). Independent work, same launch.
// ---------------------------------------------------------------------------
__global__ __launch_bounds__(256) void k_bg1(
    const unsigned* __restrict__ binned, const int* __restrict__ cursor,
    float* __restrict__ dinv, int2* __restrict__ rowse,
    unsigned* __restrict__ csr4, const float* __restrict__ feat,
    const float* __restrict__ loc, const __half* __restrict__ Wpk,
    __half* __restrict__ Y) {
    if (blockIdx.x < NBUK) {
        int k = blockIdx.x, t = threadIdx.x;
        int lane = t & 63, wv = t >> 6;
        __shared__ int ldeg[256];
        __shared__ int wcnt[256];
        __shared__ int ws4[4];
        int base = k * PADB;
        int len = cursor[k];
        ldeg[t] = 0;
        __syncthreads();
        for (int i = t; i < len; i += 256)
            atomicAdd(&ldeg[binned[base + i] >> 17], 1);
        __syncthreads();
        int degv = ldeg[t];
        int x = degv;
#pragma unroll
        for (int off = 1; off < 64; off <<= 1) {
            int u = __shfl_up(x, off);
            if (lane >= off) x += u;
        }
        if (lane == 63) ws4[wv] = x;
        __syncthreads();
        int woff = 0;
        for (int w = 0; w < wv; ++w) woff += ws4[w];
        int excl = woff + x - degv;
        int node = k * 256 + t;
        if (node < N_NODES) {
            dinv[node] = rsqrtf((float)degv + 1.0f);
            rowse[node] = make_int2(base + excl, base + excl + degv);
        }
        wcnt[t] = base + excl;
        __syncthreads();
        for (int i = t; i < len; i += 256) {
            unsigned ent = binned[base + i];
            int p = atomicAdd(&wcnt[ent >> 17], 1);
            csr4[p] = ent & 0x1FFFFu;
        }
        return;
    }
    // ---- gemm1 ----
    int wid = threadIdx.x >> 6;
    int lane = threadIdx.x & 63;
    int nb = ((blockIdx.x - NBUK) * 4 + wid) * 32;
    if (nb >= N_NODES) return;
    half8_t b[3][2];
#pragma unroll
    for (int ct = 0; ct < 3; ++ct)
#pragma unroll
        for (int kt = 0; kt < 2; ++kt)
            b[ct][kt] = *reinterpret_cast<const half8_t*>(
                Wpk + ((ct * 2 + kt) * 64 + lane) * 8);
    int r = lane & 15;
    int slot = lane >> 4;
    half8_t a[2][2];
#pragma unroll
    for (int rt = 0; rt < 2; ++rt)
#pragma unroll
        for (int kt = 0; kt < 2; ++kt) {
            int sl = kt * 4 + slot;
            int node = nb + rt * 16 + r;
            const float* sp = (sl < 6)
                                  ? feat + (size_t)node * F_RAW + sl * 8
                                  : loc + (size_t)node * F_LOC + (sl - 6) * 8;
            float4 f0 = reinterpret_cast<const float4*>(sp)[0];
            float4 f1 = reinterpret_cast<const float4*>(sp)[1];
            half8_t h;
            h[0] = (_Float16)f0.x;
            h[1] = (_Float16)f0.y;
            h[2] = (_Float16)f0.z;
            h[3] = (_Float16)f0.w;
            h[4] = (_Float16)f1.x;
            h[5] = (_Float16)f1.y;
            h[6] = (_Float16)f1.z;
            h[7] = (_Float16)f1.w;
            a[rt][kt] = h;
        }
    floatx4 acc[2][3];
#pragma unroll
    for (int rt = 0; rt < 2; ++rt)
#pragma unroll
        for (int ct = 0; ct < 3; ++ct) {
            floatx4 z = {0.f, 0.f, 0.f, 0.f};
            z = __builtin_amdgcn_mfma_f32_16x16x32_f16(a[rt][0], b[ct][0], z, 0, 0, 0);
            z = __builtin_amdgcn_mfma_f32_16x16x32_f16(a[rt][1], b[ct][1], z, 0, 0, 0);
            acc[rt][ct] = z;
        }
    int row0 = (lane >> 4) * 4;
    int col = lane & 15;
#pragma unroll
    for (int rt = 0; rt < 2; ++rt)
#pragma unroll
        for (int ct = 0; ct < 3; ++ct)
#pragma unroll
            for (int j = 0; j < 4; ++j) {
                int node = nb + rt * 16 + row0 + j;
                Y[(size_t)node * 64 + ct * 16 + col] = __float2half(acc[rt][ct][j]);
            }
    int node = nb + (lane & 31);
    int slotp = 6 + (lane >> 5);
    *reinterpret_cast<int4*>(Y + (size_t)node * 64 + slotp * 8) =
        make_int4(0, 0, 0, 0);
}

// ---------------------------------------------------------------------------
// coef: per bucket, stamp csr4[i] = (src<<14) | fp16bits(dinv[src]).
// ---------------------------------------------------------------------------
__global__ __launch_bounds__(256) void k_coef(unsigned* __restrict__ csr4,
                                              const float* __restrict__ dinv,
                                              const int* __restrict__ cursor) {
    int k = blockIdx.x;
    int end = k * PADB + cursor[k];
    for (int i = k * PADB + threadIdx.x; i < end; i += 256) {
        unsigned s = csr4[i];
        csr4[i] = (s << 14) | (unsigned)__half_as_ushort(__float2half(dinv[s]));
    }
}

// ---------------------------------------------------------------------------
// gather helpers: fp16 packed accumulate
// ---------------------------------------------------------------------------
__device__ __forceinline__ __half2 c2_from(unsigned A) {
    unsigned b = A & 0x3FFFu;
    unsigned p = b | (b << 16);
    return *reinterpret_cast<__half2*>(&p);
}

__device__ __forceinline__ void fma8h(const int4& p, __half2 c2, __half2 a[4]) {
    const __half2* h = reinterpret_cast<const __half2*>(&p);
#pragma unroll
    for (int j = 0; j < 4; ++j) a[j] = __hfma2(h[j], c2, a[j]);
}

__device__ __forceinline__ __half2 shfl_xor_h2(__half2 v, int m) {
    int i = *reinterpret_cast<int*>(&v);
    i = __shfl_xor(i, m);
    return *reinterpret_cast<__half2*>(&i);
}

// ---------------------------------------------------------------------------
// fused agg1 + gemm2: 512-thread block owns 32 nodes (8 waves x 4 nodes).
// Phase 1: gather-agg h1 -> x1 row [relu(...)|loc] -> LDS.
// Phase 2: wave w computes (rt,ct)=(w>>2,w&3) tile of GEMM2, writes h2.
// ---------------------------------------------------------------------------
__global__ __launch_bounds__(512) void k_aggemm(
    const __half* __restrict__ h1h, const float* __restrict__ dinv,
    const int2* __restrict__ rowse, const unsigned* __restrict__ csr4,
    const float* __restrict__ loc, const float* __restrict__ b1,
    const __half* __restrict__ Wpk2, __half* __restrict__ h2h) {
    __shared__ __align__(16) char lds_x1[32 * LROW];
    int t = threadIdx.x;
    int w = t >> 6;
    int lane = t & 63;
    int grp = lane >> 3;
    int l8 = lane & 7;
    int nb = blockIdx.x * 32;
    const char* h1l = reinterpret_cast<const char*>(h1h) + (l8 << 4);
#pragma unroll
    for (int it = 0; it < 4; ++it) {
        int nl = w * 4 + it;
        int node = nb + nl;
        int2 se = rowse[node];
        int r0 = se.x, r1 = se.y;
        float di = dinv[node];
        int4 hs = *reinterpret_cast<const int4*>(h1l + ((size_t)node << 7));
        int len = r1 - r0;
        int L = (len + 7) >> 3;
        int gs = r0 + grp * L;
        int ge = gs + L;
        if (ge > r1) ge = r1;
        __half2 z2 = __float2half2_rn(0.f);
        __half2 a0[4] = {z2, z2, z2, z2};
        __half2 a1[4] = {z2, z2, z2, z2};
        int e = gs;
        for (; e + 1 < ge; e += 2) {
            unsigned A = csr4[e];
            unsigned B = csr4[e + 1];
            int4 vA = *reinterpret_cast<const int4*>(h1l + ((A >> 14) << 7));
            int4 vB = *reinterpret_cast<const int4*>(h1l + ((B >> 14) << 7));
            fma8h(vA, c2_from(A), a0);
            fma8h(vB, c2_from(B), a1);
        }
        if (e < ge) {
            unsigned A = csr4[e];
            int4 vA = *reinterpret_cast<const int4*>(h1l + ((A >> 14) << 7));
            fma8h(vA, c2_from(A), a0);
        }
#pragma unroll
        for (int j = 0; j < 4; ++j) a0[j] = __hadd2(a0[j], a1[j]);
#pragma unroll
        for (int j = 0; j < 4; ++j) {
            a0[j] = __hadd2(a0[j], shfl_xor_h2(a0[j], 8));
            a0[j] = __hadd2(a0[j], shfl_xor_h2(a0[j], 16));
            a0[j] = __hadd2(a0[j], shfl_xor_h2(a0[j], 32));
        }
        if (lane < 8) {
            __half2 q[4];
            if (l8 < 6) {
                float d2 = di * di;
                const float4* b1v = reinterpret_cast<const float4*>(b1);
                float4 bA = b1v[l8 * 2];
                float4 bB = b1v[l8 * 2 + 1];
                float bb[8] = {bA.x, bA.y, bA.z, bA.w, bB.x, bB.y, bB.z, bB.w};
                const __half2* hh = reinterpret_cast<const __half2*>(&hs);
#pragma unroll
                for (int j = 0; j < 4; ++j) {
                    float2 tt = __half22float2(hh[j]);
                    float2 ag = __half22float2(a0[j]);
                    float o0 =
                        fmaxf(fmaf(ag.x, di, fmaf(tt.x, d2, bb[2 * j])), 0.f);
                    float o1 = fmaxf(
                        fmaf(ag.y, di, fmaf(tt.y, d2, bb[2 * j + 1])), 0.f);
                    q[j] = __halves2half2(__float2half(o0), __float2half(o1));
                }
            } else {
                const float* lp = loc + (size_t)node * F_LOC + (l8 - 6) * 8;
                float4 f0 = reinterpret_cast<const float4*>(lp)[0];
                float4 f1 = reinterpret_cast<const float4*>(lp)[1];
                q[0] = __halves2half2(__float2half(f0.x), __float2half(f0.y));
                q[1] = __halves2half2(__float2half(f0.z), __float2half(f0.w));
                q[2] = __halves2half2(__float2half(f1.x), __float2half(f1.y));
                q[3] = __halves2half2(__float2half(f1.z), __float2half(f1.w));
            }
            *reinterpret_cast<int4*>(&lds_x1[nl * LROW + l8 * 16]) =
                *reinterpret_cast<int4*>(q);
        }
    }
    __syncthreads();
    int rt = w >> 2;
    int ct = w & 3;
    half8_t bfr[2];
#pragma unroll
    for (int kt = 0; kt < 2; ++kt)
        bfr[kt] = *reinterpret_cast<const half8_t*>(
            Wpk2 + ((ct * 2 + kt) * 64 + lane) * 8);
    int r = lane & 15;
    int ks = (lane >> 4) * 8;
    half8_t afr[2];
#pragma unroll
    for (int kt = 0; kt < 2; ++kt)
        afr[kt] = *reinterpret_cast<const half8_t*>(
            &lds_x1[(rt * 16 + r) * LROW + kt * 64 + ks * 2]);
    floatx4 z = {0.f, 0.f, 0.f, 0.f};
    z = __builtin_amdgcn_mfma_f32_16x16x32_f16(afr[0], bfr[0], z, 0, 0, 0);
    z = __builtin_amdgcn_mfma_f32_16x16x32_f16(afr[1], bfr[1], z, 0, 0, 0);
    int row0 = (lane >> 4) * 4;
    int col = lane & 15;
#pragma unroll
    for (int j = 0; j < 4; ++j) {
        int node = nb + rt * 16 + row0 + j;
        h2h[(size_t)node * 64 + ct * 16 + col] = __float2half(z[j]);
    }
}

// ---------------------------------------------------------------------------
// agg2 + self + bias -> out (fp32)
// ---------------------------------------------------------------------------
__global__ __launch_bounds__(256) void k_out(
    const __half* __restrict__ h2h, const float* __restrict__ dinv,
    const int2* __restrict__ rowse, const unsigned* __restrict__ csr4,
    const float* __restrict__ b2, float* __restrict__ out) {
    int wave = threadIdx.x >> 6;
    int lane = threadIdx.x & 63;
    int grp = lane >> 3;
    int l8 = lane & 7;
    int node = blockIdx.x * 4 + wave;
    if (node >= N_NODES) return;
    int2 se = rowse[node];
    int r0 = se.x, r1 = se.y;
    const char* h2l = reinterpret_cast<const char*>(h2h) + (l8 << 4);
    float di = dinv[node];
    int4 hs = *reinterpret_cast<const int4*>(h2l + ((size_t)node << 7));
    int len = r1 - r0;
    int L = (len + 7) >> 3;
    int gs = r0 + grp * L;
    int ge = gs + L;
    if (ge > r1) ge = r1;
    __half2 z2 = __float2half2_rn(0.f);
    __half2 a0[4] = {z2, z2, z2, z2};
    __half2 a1[4] = {z2, z2, z2, z2};
    int e = gs;
    for (; e + 1 < ge; e += 2) {
        unsigned A = csr4[e];
        unsigned B = csr4[e + 1];
        int4 vA = *reinterpret_cast<const int4*>(h2l + ((A >> 14) << 7));
        int4 vB = *reinterpret_cast<const int4*>(h2l + ((B >> 14) << 7));
        fma8h(vA, c2_from(A), a0);
        fma8h(vB, c2_from(B), a1);
    }
    if (e < ge) {
        unsigned A = csr4[e];
        int4 vA = *reinterpret_cast<const int4*>(h2l + ((A >> 14) << 7));
        fma8h(vA, c2_from(A), a0);
    }
#pragma unroll
    for (int j = 0; j < 4; ++j) a0[j] = __hadd2(a0[j], a1[j]);
#pragma unroll
    for (int j = 0; j < 4; ++j) {
        a0[j] = __hadd2(a0[j], shfl_xor_h2(a0[j], 8));
        a0[j] = __hadd2(a0[j], shfl_xor_h2(a0[j], 16));
        a0[j] = __hadd2(a0[j], shfl_xor_h2(a0[j], 32));
    }
    if (lane < 8) {
        float d2 = di * di;
        const float4* b2v = reinterpret_cast<const float4*>(b2);
        float4 bA = b2v[l8 * 2];
        float4 bB = b2v[l8 * 2 + 1];
        float bb[8] = {bA.x, bA.y, bA.z, bA.w, bB.x, bB.y, bB.z, bB.w};
        const __half2* hh = reinterpret_cast<const __half2*>(&hs);
        float o[8];
#pragma unroll
        for (int j = 0; j < 4; ++j) {
            float2 t = __half22float2(hh[j]);
            float2 ag = __half22float2(a0[j]);
            o[2 * j] = fmaf(ag.x, di, fmaf(t.x, d2, bb[2 * j]));
            o[2 * j + 1] = fmaf(ag.y, di, fmaf(t.y, d2, bb[2 * j + 1]));
        }
        float4* ov = reinterpret_cast<float4*>(out + (size_t)node * F_OUT);
        ov[l8 * 2] = make_float4(o[0], o[1], o[2], o[3]);
        ov[l8 * 2 + 1] = make_float4(o[4], o[5], o[6], o[7]);
    }
}

extern "C" void kernel_launch(void* const* d_in, const int* in_sizes, int n_in,
                              void* d_out, int out_size, void* d_ws,
                              size_t ws_size, hipStream_t stream) {
    const void* edges = d_in[0];
    const float* feat = (const float*)d_in[1];
    const float* loc = (const float*)d_in[2];
    const float* W1 = (const float*)d_in[3];
    const float* b1 = (const float*)d_in[4];
    const float* W2 = (const float*)d_in[5];
    const float* b2 = (const float*)d_in[6];
    float* out = (float*)d_out;

    // All offsets multiples of 128 (128B feature rows must be line-aligned:
    // r13's 32-mod-128 base cost +50% gather fetch).
    char* ws = (char*)d_ws;
    float* dinv = (float*)(ws + 0);                //    400,000
    int2* rowse = (int2*)(ws + 400000);            //    800,000
    int* cursor = (int*)(ws + 1200000);            //      1,664 (pad)
    unsigned* binned = (unsigned*)(ws + 1201664);  //  6,406,144
    unsigned* csr4 = (unsigned*)(ws + 7607808);    //  6,406,144
    __half* h1h = (__half*)(ws + 14013952);        // 12,800,000
    __half* h2h = (__half*)(ws + 26813952);        // 12,800,000
    __half* wpk1 = (__half*)(ws + 39613952);       //      6,144
    __half* wpk2 = (__half*)(ws + 39620096);       //      8,192

    hipMemsetAsync(cursor, 0, NBUK * 4, stream);

    // ---- CSR binning + W pack (fused grid) ----
    k_prep2<<<NB2 + 2, 512, 0, stream>>>(edges, W1, wpk1, W2, wpk2, cursor,
                                         binned);
    // ---- bucket build + gemm1 (fused grid; independent halves) ----
    k_bg1<<<NBUK + GB1, 256, 0, stream>>>(binned, cursor, dinv, rowse, csr4,
                                          feat, loc, wpk1, h1h);
    // ---- coef stamp ----
    k_coef<<<NBUK, 256, 0, stream>>>(csr4, dinv, cursor);
    // ---- fused agg1 + gemm2 ----
    k_aggemm<<<N_NODES / 32, 512, 0, stream>>>(h1h, dinv, rowse, csr4, loc,
                                               b1, wpk2, h2h);
    // ---- agg2 -> out ----
    k_out<<<(N_NODES + 3) / 4, 256, 0, stream>>>(h2h, dinv, rowse, csr4, b2,
                                                 out);
}